// Round 1
// baseline (414.349 us; speedup 1.0000x reference)
//
#include <hip/hip_runtime.h>

#define SCALE 22.627416997969522f
#define LNEPS 1e-5f

using short8 = __attribute__((ext_vector_type(8))) short;
using f32x4  = __attribute__((ext_vector_type(4))) float;

static __device__ __forceinline__ short f2bf(float f){
  unsigned u = __builtin_bit_cast(unsigned, f);
  u += 0x7FFFu + ((u >> 16) & 1u);
  return (short)(u >> 16);
}

// C[M x 512*NOUT] = act(A[M x K] @ W[K x 512] + bias), NOUT separate W/bias/C.
// Block: 256 threads = 4 waves; block tile 64(M) x 64(N); wave tile 32x32 (2x2 MFMA).
template<int NOUT, bool RELU>
__global__ __launch_bounds__(256) void gemm_k(
    const float* __restrict__ A, int K,
    const float* __restrict__ W0, const float* __restrict__ W1, const float* __restrict__ W2,
    const float* __restrict__ B0, const float* __restrict__ B1, const float* __restrict__ B2,
    float* __restrict__ C0, float* __restrict__ C1, float* __restrict__ C2)
{
  int bm = blockIdx.x;
  int nglob = blockIdx.y * 64;
  int sel  = nglob >> 9;
  int ncol = nglob & 511;
  const float* W  = (sel==0) ? W0 : (sel==1) ? W1 : W2;
  const float* Bv = (sel==0) ? B0 : (sel==1) ? B1 : B2;
  float*       C  = (sel==0) ? C0 : (sel==1) ? C1 : C2;

  int wave = threadIdx.x >> 6, lane = threadIdx.x & 63;
  int wm = (wave >> 1) * 32, wn = (wave & 1) * 32;
  int lr = lane & 15, kg = lane >> 4;

  int rowA0 = bm*64 + wm + lr;   // + mi*16 for A loads
  int colB0 = ncol + wn + lr;    // + ni*16 for B loads / C stores

  f32x4 acc[2][2] = {};

  for (int k0 = 0; k0 < K; k0 += 32) {
    int kk = k0 + kg*8;
    short8 af[2], bfr[2];
#pragma unroll
    for (int mi = 0; mi < 2; ++mi) {
      const float* ap = A + (size_t)(rowA0 + mi*16)*K + kk;
      float4 u = *(const float4*)ap;
      float4 v = *(const float4*)(ap + 4);
      short8 t;
      t[0]=f2bf(u.x); t[1]=f2bf(u.y); t[2]=f2bf(u.z); t[3]=f2bf(u.w);
      t[4]=f2bf(v.x); t[5]=f2bf(v.y); t[6]=f2bf(v.z); t[7]=f2bf(v.w);
      af[mi] = t;
    }
#pragma unroll
    for (int ni = 0; ni < 2; ++ni) {
      const float* bp = W + (size_t)kk*512 + colB0 + ni*16;
      short8 t;
#pragma unroll
      for (int i = 0; i < 8; ++i) t[i] = f2bf(bp[(size_t)i*512]);
      bfr[ni] = t;
    }
#pragma unroll
    for (int mi = 0; mi < 2; ++mi)
#pragma unroll
      for (int ni = 0; ni < 2; ++ni)
        acc[mi][ni] = __builtin_amdgcn_mfma_f32_16x16x32_bf16(af[mi], bfr[ni], acc[mi][ni], 0, 0, 0);
  }

#pragma unroll
  for (int mi = 0; mi < 2; ++mi)
#pragma unroll
    for (int ni = 0; ni < 2; ++ni) {
      int col = colB0 + ni*16;
      float bia = Bv[col];
#pragma unroll
      for (int r = 0; r < 4; ++r) {
        int row = bm*64 + wm + mi*16 + kg*4 + r;
        float vv = acc[mi][ni][r] + bia;
        if (RELU) vv = fmaxf(vv, 0.f);
        C[(size_t)row*512 + col] = vv;
      }
    }
}

// One block (4 waves) per token. Energies via wave-wide coalesced dots,
// per-head softmax (incl. 1/SCALE), PV, then fused residual + LayerNorm.
template<int KLOC>
__global__ __launch_bounds__(256) void attn_k(
    const float* __restrict__ Qm, const float* __restrict__ Km, const float* __restrict__ Vm,
    const int* __restrict__ Aidx,
    const float* __restrict__ resid,
    const float* __restrict__ gma, const float* __restrict__ bta,
    float* __restrict__ outp, float* __restrict__ attOut)
{
  __shared__ float q_s[512];
  __shared__ float att_s[8*KLOC];
  __shared__ float o_s[512];
  __shared__ int   idx_s[KLOC];
  __shared__ float red_s[8];

  int n = blockIdx.x;
  int t = threadIdx.x, wave = t >> 6, lane = t & 63;

  q_s[t]       = Qm[(size_t)n*512 + t];
  q_s[t + 256] = Qm[(size_t)n*512 + t + 256];
  if (t < KLOC) idx_s[t] = Aidx[(size_t)n*64 + t];
  __syncthreads();

  // energies: pair p = (h, j); each wave does 8*KLOC/4 wave-wide dot products
  constexpr int PP = 8*KLOC/4;
#pragma unroll 2
  for (int pi = 0; pi < PP; ++pi) {
    int p = wave*PP + pi;
    int h = p / KLOC, j = p % KLOC;
    float e = q_s[h*64 + lane] * Km[(size_t)idx_s[j]*512 + h*64 + lane];
    e += __shfl_xor(e, 1);  e += __shfl_xor(e, 2);  e += __shfl_xor(e, 4);
    e += __shfl_xor(e, 8);  e += __shfl_xor(e, 16); e += __shfl_xor(e, 32);
    if (lane == 0) att_s[h*KLOC + j] = e;
  }
  __syncthreads();

  // softmax per head (2 heads per wave), fold in 1/SCALE
#pragma unroll
  for (int hh = 0; hh < 2; ++hh) {
    int h = wave*2 + hh;
    float e = (lane < KLOC) ? att_s[h*KLOC + lane] : -1e30f;
    float m = e;
    m = fmaxf(m, __shfl_xor(m, 1));  m = fmaxf(m, __shfl_xor(m, 2));
    m = fmaxf(m, __shfl_xor(m, 4));  m = fmaxf(m, __shfl_xor(m, 8));
    m = fmaxf(m, __shfl_xor(m, 16)); m = fmaxf(m, __shfl_xor(m, 32));
    float ex = (lane < KLOC) ? __expf(e - m) : 0.f;
    float s = ex;
    s += __shfl_xor(s, 1);  s += __shfl_xor(s, 2);  s += __shfl_xor(s, 4);
    s += __shfl_xor(s, 8);  s += __shfl_xor(s, 16); s += __shfl_xor(s, 32);
    if (lane < KLOC) att_s[h*KLOC + lane] = ex / (s * SCALE);
  }
  __syncthreads();

  // PV: out[h][d] = sum_j att[h][j] * V[idx_j][h*64+d]; lane = d
#pragma unroll
  for (int hh = 0; hh < 2; ++hh) {
    int h = wave*2 + hh;
    float a0=0.f, a1=0.f, a2=0.f, a3=0.f;
    const float* vb = Vm + h*64 + lane;
#pragma unroll
    for (int j = 0; j < KLOC; j += 4) {
      a0 += att_s[h*KLOC + j + 0] * vb[(size_t)idx_s[j + 0]*512];
      a1 += att_s[h*KLOC + j + 1] * vb[(size_t)idx_s[j + 1]*512];
      a2 += att_s[h*KLOC + j + 2] * vb[(size_t)idx_s[j + 2]*512];
      a3 += att_s[h*KLOC + j + 3] * vb[(size_t)idx_s[j + 3]*512];
    }
    o_s[h*64 + lane] = (a0 + a1) + (a2 + a3);
  }
  __syncthreads();

  // residual + LayerNorm over the 512-row
  float x0 = o_s[t]       + resid[(size_t)n*512 + t];
  float x1 = o_s[t + 256] + resid[(size_t)n*512 + t + 256];
  float s  = x0 + x1, ss = x0*x0 + x1*x1;
  s += __shfl_xor(s, 1);  ss += __shfl_xor(ss, 1);
  s += __shfl_xor(s, 2);  ss += __shfl_xor(ss, 2);
  s += __shfl_xor(s, 4);  ss += __shfl_xor(ss, 4);
  s += __shfl_xor(s, 8);  ss += __shfl_xor(ss, 8);
  s += __shfl_xor(s, 16); ss += __shfl_xor(ss, 16);
  s += __shfl_xor(s, 32); ss += __shfl_xor(ss, 32);
  if (lane == 0) { red_s[wave] = s; red_s[4 + wave] = ss; }
  __syncthreads();
  float tot  = red_s[0] + red_s[1] + red_s[2] + red_s[3];
  float tots = red_s[4] + red_s[5] + red_s[6] + red_s[7];
  float mean = tot  * (1.0f/512.0f);
  float var  = tots * (1.0f/512.0f) - mean*mean;
  float rstd = rsqrtf(var + LNEPS);
  outp[(size_t)n*512 + t]       = (x0 - mean)*rstd*gma[t]       + bta[t];
  outp[(size_t)n*512 + t + 256] = (x1 - mean)*rstd*gma[t + 256] + bta[t + 256];
  if (attOut != nullptr && t == 0) attOut[n] = 8.0f / SCALE;
}

extern "C" void kernel_launch(void* const* d_in, const int* in_sizes, int n_in,
                              void* d_out, int out_size, void* d_ws, size_t ws_size,
                              hipStream_t stream)
{
  const float* x   = (const float*)d_in[0];
  const int*   A   = (const int*)  d_in[1];
  const float* Wfc = (const float*)d_in[2];
  const float* bfc = (const float*)d_in[3];
  const float* Wq1 = (const float*)d_in[4];
  const float* bq1 = (const float*)d_in[5];
  const float* Wk1 = (const float*)d_in[6];
  const float* bk1 = (const float*)d_in[7];
  const float* Wv1 = (const float*)d_in[8];
  const float* bv1 = (const float*)d_in[9];
  const float* g1  = (const float*)d_in[10];
  const float* be1 = (const float*)d_in[11];
  const float* Wq2 = (const float*)d_in[12];
  const float* bq2 = (const float*)d_in[13];
  const float* Wk2 = (const float*)d_in[14];
  const float* bk2 = (const float*)d_in[15];
  const float* Wv2 = (const float*)d_in[16];
  const float* bv2 = (const float*)d_in[17];
  const float* g2  = (const float*)d_in[18];
  const float* be2 = (const float*)d_in[19];

  float* ws = (float*)d_ws;
  const size_t SZ = (size_t)2048*512;
  float* embs = ws;
  float* b1   = ws + SZ;
  float* q    = ws + 2*SZ;
  float* k    = ws + 3*SZ;
  float* v    = ws + 4*SZ;
  float* out  = (float*)d_out;
  float* att2 = out + SZ;

  dim3 blk(256);
  // embs = relu(x @ W_fc + b_fc)
  gemm_k<1,true><<<dim3(32, 8), blk, 0, stream>>>(x, 1024,
      Wfc, nullptr, nullptr, bfc, nullptr, nullptr, embs, nullptr, nullptr);
  // q/k/v = embs @ Wq1/Wk1/Wv1 + b
  gemm_k<3,false><<<dim3(32, 24), blk, 0, stream>>>(embs, 512,
      Wq1, Wk1, Wv1, bq1, bk1, bv1, q, k, v);
  // attn1 (16 keys) + residual(embs) + LN -> b1
  attn_k<16><<<dim3(2048), blk, 0, stream>>>(q, k, v, A, embs, g1, be1, b1, nullptr);
  // q/k/v = b1 @ Wq2/Wk2/Wv2 + b
  gemm_k<3,false><<<dim3(32, 24), blk, 0, stream>>>(b1, 512,
      Wq2, Wk2, Wv2, bq2, bk2, bv2, q, k, v);
  // attn2 (64 keys) + residual(b1) + LN -> b2 (d_out), plus Att2
  attn_k<64><<<dim3(2048), blk, 0, stream>>>(q, k, v, A, b1, g2, be2, out, att2);
}

// Round 3
// 234.685 us; speedup vs baseline: 1.7656x; 1.7656x over previous
//
#include <hip/hip_runtime.h>

#define SCALE 22.627416997969522f
#define LNEPS 1e-5f

using short8 = __attribute__((ext_vector_type(8))) short;
using f32x4  = __attribute__((ext_vector_type(4))) float;
typedef unsigned short u16;

static __device__ __forceinline__ short f2bf(float f){
  unsigned u = __builtin_bit_cast(unsigned, f);
  u += 0x7FFFu + ((u >> 16) & 1u);
  return (short)(u >> 16);
}
static __device__ __forceinline__ float bf2f(u16 u){
  unsigned v = ((unsigned)u) << 16;
  return __builtin_bit_cast(float, v);
}

// C = act(A[M x K] @ W[K x 512] + bias).
// SPLIT3: blockIdx.y spans 3 weight sets; output 0 stored f32, outputs 1,2 stored bf16.
// Block: 256 threads = 4 waves; block tile 64(M) x 64(N); wave tile 32x32 (2x2 MFMA).
template<bool RELU, bool SPLIT3>
__global__ __launch_bounds__(256) void gemm_k(
    const float* __restrict__ A, int K,
    const float* __restrict__ W0, const float* __restrict__ W1, const float* __restrict__ W2,
    const float* __restrict__ B0, const float* __restrict__ B1, const float* __restrict__ B2,
    float* __restrict__ C0, u16* __restrict__ C1, u16* __restrict__ C2)
{
  int bm = blockIdx.x;
  int nglob = blockIdx.y * 64;
  int sel  = SPLIT3 ? (nglob >> 9) : 0;
  int ncol = nglob & 511;
  const float* W  = (sel==0) ? W0 : (sel==1) ? W1 : W2;
  const float* Bv = (sel==0) ? B0 : (sel==1) ? B1 : B2;

  int wave = threadIdx.x >> 6, lane = threadIdx.x & 63;
  int wm = (wave >> 1) * 32, wn = (wave & 1) * 32;
  int lr = lane & 15, kg = lane >> 4;

  int rowA0 = bm*64 + wm + lr;
  int colB0 = ncol + wn + lr;

  f32x4 acc[2][2] = {};

  for (int k0 = 0; k0 < K; k0 += 32) {
    int kk = k0 + kg*8;
    short8 af[2], bfr[2];
#pragma unroll
    for (int mi = 0; mi < 2; ++mi) {
      const float* ap = A + (size_t)(rowA0 + mi*16)*K + kk;
      float4 u = *(const float4*)ap;
      float4 v = *(const float4*)(ap + 4);
      short8 t;
      t[0]=f2bf(u.x); t[1]=f2bf(u.y); t[2]=f2bf(u.z); t[3]=f2bf(u.w);
      t[4]=f2bf(v.x); t[5]=f2bf(v.y); t[6]=f2bf(v.z); t[7]=f2bf(v.w);
      af[mi] = t;
    }
#pragma unroll
    for (int ni = 0; ni < 2; ++ni) {
      const float* bp = W + (size_t)kk*512 + colB0 + ni*16;
      short8 t;
#pragma unroll
      for (int i = 0; i < 8; ++i) t[i] = f2bf(bp[(size_t)i*512]);
      bfr[ni] = t;
    }
#pragma unroll
    for (int mi = 0; mi < 2; ++mi)
#pragma unroll
      for (int ni = 0; ni < 2; ++ni)
        acc[mi][ni] = __builtin_amdgcn_mfma_f32_16x16x32_bf16(af[mi], bfr[ni], acc[mi][ni], 0, 0, 0);
  }

#pragma unroll
  for (int mi = 0; mi < 2; ++mi)
#pragma unroll
    for (int ni = 0; ni < 2; ++ni) {
      int col = colB0 + ni*16;
      float bia = Bv[col];
#pragma unroll
      for (int r = 0; r < 4; ++r) {
        int row = bm*64 + wm + mi*16 + kg*4 + r;
        float vv = acc[mi][ni][r] + bia;
        if (RELU) vv = fmaxf(vv, 0.f);
        if (!SPLIT3 || sel == 0) {
          C0[(size_t)row*512 + col] = vv;
        } else {
          u16* C = (sel == 1) ? C1 : C2;
          C[(size_t)row*512 + col] = (u16)f2bf(vv);
        }
      }
    }
}

// One block (4 waves) per token. Per-lane energies (good ILP), per-head shfl
// softmax, coalesced bf16 PV, fused residual + LayerNorm.
template<int KLOC>
__global__ __launch_bounds__(256) void attn_k(
    const float* __restrict__ Qm, const u16* __restrict__ Kb, const u16* __restrict__ Vb,
    const int* __restrict__ Aidx,
    const float* __restrict__ resid,
    const float* __restrict__ gma, const float* __restrict__ bta,
    float* __restrict__ outp, float* __restrict__ attOut)
{
  __shared__ float q_s[512];
  __shared__ float att_s[8*KLOC];
  __shared__ float o_s[512];
  __shared__ int   idx_s[KLOC];
  __shared__ float red_s[8];

  int n = blockIdx.x;
  int t = threadIdx.x, w = t >> 6, lane = t & 63;

  q_s[t]       = __builtin_nontemporal_load(Qm + (size_t)n*512 + t);
  q_s[t + 256] = __builtin_nontemporal_load(Qm + (size_t)n*512 + t + 256);
  if (t < KLOC) idx_s[t] = Aidx[(size_t)n*64 + t];
  __syncthreads();

  if (KLOC == 64) {
    // each thread: energies for heads (2w, 2w+1) at key j = lane
    int idx = idx_s[lane];
    int h0 = w*2, h1 = h0 + 1;
    const u16* kp = Kb + (size_t)idx*512;
    float e0 = 0.f, e1 = 0.f;
#pragma unroll
    for (int d0 = 0; d0 < 64; d0 += 8) {
      short8 k0 = *(const short8*)(kp + h0*64 + d0);
      short8 k1 = *(const short8*)(kp + h1*64 + d0);
#pragma unroll
      for (int i = 0; i < 8; ++i) {
        e0 = fmaf(q_s[h0*64 + d0 + i], bf2f((u16)k0[i]), e0);
        e1 = fmaf(q_s[h1*64 + d0 + i], bf2f((u16)k1[i]), e1);
      }
    }
    // softmax across the full wave (64 keys per head)
#pragma unroll
    for (int hh = 0; hh < 2; ++hh) {
      float e = hh ? e1 : e0;
      float m = e;
      m = fmaxf(m, __shfl_xor(m, 1));  m = fmaxf(m, __shfl_xor(m, 2));
      m = fmaxf(m, __shfl_xor(m, 4));  m = fmaxf(m, __shfl_xor(m, 8));
      m = fmaxf(m, __shfl_xor(m, 16)); m = fmaxf(m, __shfl_xor(m, 32));
      float p = __expf(e - m);
      float s = p;
      s += __shfl_xor(s, 1);  s += __shfl_xor(s, 2);  s += __shfl_xor(s, 4);
      s += __shfl_xor(s, 8);  s += __shfl_xor(s, 16); s += __shfl_xor(s, 32);
      att_s[(h0 + hh)*64 + lane] = p / (s * SCALE);
    }
  } else {
    // KLOC==16: 128 energies (8 heads x 16 keys), 256 threads -> 2 threads per
    // energy, each covering 32 of the 64 dims.
    int h  = w*2 + (lane >> 5);     // 0..7
    int j  = lane & 15;             // 0..15
    int dh = (lane >> 4) & 1;       // 0..1 half of head-dim
    int idx = idx_s[j];
    const u16*   kp = Kb + (size_t)idx*512 + h*64 + dh*32;
    const float* qp = q_s + h*64 + dh*32;
    float e = 0.f;
#pragma unroll
    for (int d0 = 0; d0 < 32; d0 += 8) {
      short8 kk = *(const short8*)(kp + d0);
#pragma unroll
      for (int i = 0; i < 8; ++i)
        e = fmaf(qp[d0 + i], bf2f((u16)kk[i]), e);
    }
    e += __shfl_xor(e, 16);   // combine the two 32-dim halves
    float m = e;
    m = fmaxf(m, __shfl_xor(m, 1)); m = fmaxf(m, __shfl_xor(m, 2));
    m = fmaxf(m, __shfl_xor(m, 4)); m = fmaxf(m, __shfl_xor(m, 8));
    float p = __expf(e - m);
    float s = p;
    s += __shfl_xor(s, 1); s += __shfl_xor(s, 2);
    s += __shfl_xor(s, 4); s += __shfl_xor(s, 8);
    att_s[h*16 + j] = p / (s * SCALE);   // two lanes write same value: benign
  }
  __syncthreads();

  // PV: per wave 2 heads, lane = d; coalesced bf16 row-segment loads
#pragma unroll
  for (int hh = 0; hh < 2; ++hh) {
    int h = w*2 + hh;
    const u16* vbp = Vb + h*64 + lane;
    float a0=0.f, a1=0.f, a2=0.f, a3=0.f;
#pragma unroll
    for (int j = 0; j < KLOC; j += 4) {
      a0 = fmaf(att_s[h*KLOC + j + 0], bf2f(vbp[(size_t)idx_s[j + 0]*512]), a0);
      a1 = fmaf(att_s[h*KLOC + j + 1], bf2f(vbp[(size_t)idx_s[j + 1]*512]), a1);
      a2 = fmaf(att_s[h*KLOC + j + 2], bf2f(vbp[(size_t)idx_s[j + 2]*512]), a2);
      a3 = fmaf(att_s[h*KLOC + j + 3], bf2f(vbp[(size_t)idx_s[j + 3]*512]), a3);
    }
    o_s[h*64 + lane] = (a0 + a1) + (a2 + a3);
  }
  __syncthreads();

  // residual + LayerNorm over the 512-row
  float x0 = o_s[t]       + __builtin_nontemporal_load(resid + (size_t)n*512 + t);
  float x1 = o_s[t + 256] + __builtin_nontemporal_load(resid + (size_t)n*512 + t + 256);
  float s  = x0 + x1, ss = x0*x0 + x1*x1;
  s += __shfl_xor(s, 1);  ss += __shfl_xor(ss, 1);
  s += __shfl_xor(s, 2);  ss += __shfl_xor(ss, 2);
  s += __shfl_xor(s, 4);  ss += __shfl_xor(ss, 4);
  s += __shfl_xor(s, 8);  ss += __shfl_xor(ss, 8);
  s += __shfl_xor(s, 16); ss += __shfl_xor(ss, 16);
  s += __shfl_xor(s, 32); ss += __shfl_xor(ss, 32);
  if (lane == 0) { red_s[w] = s; red_s[4 + w] = ss; }
  __syncthreads();
  float tot  = red_s[0] + red_s[1] + red_s[2] + red_s[3];
  float tots = red_s[4] + red_s[5] + red_s[6] + red_s[7];
  float mean = tot  * (1.0f/512.0f);
  float var  = tots * (1.0f/512.0f) - mean*mean;
  float rstd = rsqrtf(var + LNEPS);
  float y0 = (x0 - mean)*rstd*gma[t]       + bta[t];
  float y1 = (x1 - mean)*rstd*gma[t + 256] + bta[t + 256];
  __builtin_nontemporal_store(y0, outp + (size_t)n*512 + t);
  __builtin_nontemporal_store(y1, outp + (size_t)n*512 + t + 256);
  if (attOut != nullptr && t == 0) attOut[n] = 8.0f / SCALE;
}

extern "C" void kernel_launch(void* const* d_in, const int* in_sizes, int n_in,
                              void* d_out, int out_size, void* d_ws, size_t ws_size,
                              hipStream_t stream)
{
  const float* x   = (const float*)d_in[0];
  const int*   A   = (const int*)  d_in[1];
  const float* Wfc = (const float*)d_in[2];
  const float* bfc = (const float*)d_in[3];
  const float* Wq1 = (const float*)d_in[4];
  const float* bq1 = (const float*)d_in[5];
  const float* Wk1 = (const float*)d_in[6];
  const float* bk1 = (const float*)d_in[7];
  const float* Wv1 = (const float*)d_in[8];
  const float* bv1 = (const float*)d_in[9];
  const float* g1  = (const float*)d_in[10];
  const float* be1 = (const float*)d_in[11];
  const float* Wq2 = (const float*)d_in[12];
  const float* bq2 = (const float*)d_in[13];
  const float* Wk2 = (const float*)d_in[14];
  const float* bk2 = (const float*)d_in[15];
  const float* Wv2 = (const float*)d_in[16];
  const float* bv2 = (const float*)d_in[17];
  const float* g2  = (const float*)d_in[18];
  const float* be2 = (const float*)d_in[19];

  float* ws = (float*)d_ws;
  const size_t SZ = (size_t)2048*512;
  float* embs = ws;             // f32
  float* b1   = ws + SZ;        // f32
  float* q    = ws + 2*SZ;      // f32
  u16*   kb   = (u16*)(ws + 3*SZ);           // bf16
  u16*   vb   = (u16*)(ws + 3*SZ) + SZ;      // bf16
  float* out  = (float*)d_out;
  float* att2 = out + SZ;

  dim3 blk(256);
  // embs = relu(x @ W_fc + b_fc)
  gemm_k<true,false><<<dim3(32, 8), blk, 0, stream>>>(x, 1024,
      Wfc, nullptr, nullptr, bfc, nullptr, nullptr, embs, nullptr, nullptr);
  // q (f32), k/v (bf16) = embs @ Wq1/Wk1/Wv1 + b
  gemm_k<false,true><<<dim3(32, 24), blk, 0, stream>>>(embs, 512,
      Wq1, Wk1, Wv1, bq1, bk1, bv1, q, kb, vb);
  // attn1 (16 keys) + residual(embs) + LN -> b1
  attn_k<16><<<dim3(2048), blk, 0, stream>>>(q, kb, vb, A, embs, g1, be1, b1, nullptr);
  // q/k/v for layer 2
  gemm_k<false,true><<<dim3(32, 24), blk, 0, stream>>>(b1, 512,
      Wq2, Wk2, Wv2, bq2, bk2, bv2, q, kb, vb);
  // attn2 (64 keys) + residual(b1) + LN -> b2 (d_out), plus Att2
  attn_k<64><<<dim3(2048), blk, 0, stream>>>(q, kb, vb, A, b1, g2, be2, out, att2);
}

// Round 5
// 221.469 us; speedup vs baseline: 1.8709x; 1.0597x over previous
//
#include <hip/hip_runtime.h>

#define SCALE 22.627416997969522f
#define LNEPS 1e-5f

using short8 = __attribute__((ext_vector_type(8))) short;
using f32x4  = __attribute__((ext_vector_type(4))) float;
typedef unsigned short u16;
using u16x4 = __attribute__((ext_vector_type(4))) u16;

static __device__ __forceinline__ short f2bf(float f){
  unsigned u = __builtin_bit_cast(unsigned, f);
  u += 0x7FFFu + ((u >> 16) & 1u);
  return (short)(u >> 16);
}
static __device__ __forceinline__ float bf2f(u16 u){
  unsigned v = ((unsigned)u) << 16;
  return __builtin_bit_cast(float, v);
}

// ---- prep: plain f32 -> bf16 convert (vectorized), n multiple of 1024 ----
__global__ __launch_bounds__(256) void cvt_k(const float* __restrict__ src,
                                             u16* __restrict__ dst, int n)
{
  int i = (blockIdx.x * 256 + threadIdx.x) * 4;
  if (i >= n) return;
  float4 v = *(const float4*)(src + i);
  u16x4 o;
  o[0] = (u16)f2bf(v.x); o[1] = (u16)f2bf(v.y);
  o[2] = (u16)f2bf(v.z); o[3] = (u16)f2bf(v.w);
  *(u16x4*)(dst + i) = o;
}

// ---- prep: W [K][N] f32  ->  Wt [N][K] bf16, LDS-tiled transpose ----
__global__ __launch_bounds__(256) void tr_k(
    const float* __restrict__ W0, const float* __restrict__ W1,
    const float* __restrict__ W2, const float* __restrict__ W3,
    const float* __restrict__ W4, const float* __restrict__ W5,
    u16* __restrict__ T0, u16* __restrict__ T1, u16* __restrict__ T2,
    u16* __restrict__ T3, u16* __restrict__ T4, u16* __restrict__ T5,
    int K, int N)
{
  int z = blockIdx.z;
  const float* W = (z==0)?W0:(z==1)?W1:(z==2)?W2:(z==3)?W3:(z==4)?W4:W5;
  u16*         T = (z==0)?T0:(z==1)?T1:(z==2)?T2:(z==3)?T3:(z==4)?T4:T5;

  __shared__ float tile[32][33];
  int n0 = blockIdx.x * 32, k0 = blockIdx.y * 32;
  int tx = threadIdx.x & 31, ty = threadIdx.x >> 5;  // 32 x 8
#pragma unroll
  for (int i = 0; i < 32; i += 8)
    tile[ty + i][tx] = W[(size_t)(k0 + ty + i) * N + n0 + tx];
  __syncthreads();
#pragma unroll
  for (int i = 0; i < 32; i += 8)
    T[(size_t)(n0 + ty + i) * K + k0 + tx] = (u16)f2bf(tile[tx][ty + i]);
}

// ---- GEMM: C = act(A_bf16[MxK] @ Wt_bf16[N][K]^T + bias) ----
// SPLIT3: blockIdx.y spans 3 weight sets, all outputs bf16.
// else: single set, dual store f32 (C0f) + bf16 (C0b).
// Block 256 thr = 4 waves; tile 64x64; wave 32x32 (2x2 MFMA 16x16x32).
template<bool RELU, bool SPLIT3>
__global__ __launch_bounds__(256) void gemm_k(
    const u16* __restrict__ A, int K,
    const u16* __restrict__ T0, const u16* __restrict__ T1, const u16* __restrict__ T2,
    const float* __restrict__ B0, const float* __restrict__ B1, const float* __restrict__ B2,
    float* __restrict__ C0f, u16* __restrict__ C0b,
    u16* __restrict__ C1, u16* __restrict__ C2)
{
  int bm = blockIdx.x;
  int nglob = blockIdx.y * 64;
  int sel  = SPLIT3 ? (nglob >> 9) : 0;
  int ncol = nglob & 511;
  const u16*   T  = (sel==0) ? T0 : (sel==1) ? T1 : T2;
  const float* Bv = (sel==0) ? B0 : (sel==1) ? B1 : B2;

  int wave = threadIdx.x >> 6, lane = threadIdx.x & 63;
  int wm = (wave >> 1) * 32, wn = (wave & 1) * 32;
  int lr = lane & 15, kg = lane >> 4;

  const u16* Ab = A + (size_t)(bm*64 + wm + lr) * K + kg*8;
  const u16* Bt = T + (size_t)(ncol + wn + lr) * K + kg*8;

  f32x4 acc[2][2] = {};

#pragma unroll 4
  for (int k0 = 0; k0 < K; k0 += 32) {
    short8 a0 = *(const short8*)(Ab + k0);
    short8 a1 = *(const short8*)(Ab + (size_t)16*K + k0);
    short8 b0 = *(const short8*)(Bt + k0);
    short8 b1 = *(const short8*)(Bt + (size_t)16*K + k0);
    acc[0][0] = __builtin_amdgcn_mfma_f32_16x16x32_bf16(a0, b0, acc[0][0], 0, 0, 0);
    acc[0][1] = __builtin_amdgcn_mfma_f32_16x16x32_bf16(a0, b1, acc[0][1], 0, 0, 0);
    acc[1][0] = __builtin_amdgcn_mfma_f32_16x16x32_bf16(a1, b0, acc[1][0], 0, 0, 0);
    acc[1][1] = __builtin_amdgcn_mfma_f32_16x16x32_bf16(a1, b1, acc[1][1], 0, 0, 0);
  }

#pragma unroll
  for (int mi = 0; mi < 2; ++mi)
#pragma unroll
    for (int ni = 0; ni < 2; ++ni) {
      int col = ncol + wn + ni*16 + lr;
      float bia = Bv[col];
#pragma unroll
      for (int r = 0; r < 4; ++r) {
        int row = bm*64 + wm + mi*16 + kg*4 + r;
        float vv = acc[mi][ni][r] + bia;
        if (RELU) vv = fmaxf(vv, 0.f);
        if (SPLIT3) {
          u16* C = (sel==0) ? C0b : (sel==1) ? C1 : C2;
          C[(size_t)row*512 + col] = (u16)f2bf(vv);
        } else {
          C0f[(size_t)row*512 + col] = vv;
          C0b[(size_t)row*512 + col] = (u16)f2bf(vv);
        }
      }
    }
}

// One block (4 waves) per token. Per-lane energies, shfl softmax, bf16 PV,
// fused residual + LayerNorm. Optional bf16 secondary output.
template<int KLOC>
__global__ __launch_bounds__(256) void attn_k(
    const u16* __restrict__ Qb, const u16* __restrict__ Kb, const u16* __restrict__ Vb,
    const int* __restrict__ Aidx,
    const float* __restrict__ resid,
    const float* __restrict__ gma, const float* __restrict__ bta,
    float* __restrict__ outp, u16* __restrict__ outb, float* __restrict__ attOut)
{
  __shared__ float q_s[512];
  __shared__ float att_s[8*KLOC];
  __shared__ float o_s[512];
  __shared__ int   idx_s[KLOC];
  __shared__ float red_s[8];

  int n = blockIdx.x;
  int t = threadIdx.x, w = t >> 6, lane = t & 63;

  q_s[t]       = bf2f(Qb[(size_t)n*512 + t]);
  q_s[t + 256] = bf2f(Qb[(size_t)n*512 + t + 256]);
  if (t < KLOC) idx_s[t] = Aidx[(size_t)n*64 + t];
  __syncthreads();

  if (KLOC == 64) {
    int idx = idx_s[lane];
    int h0 = w*2, h1 = h0 + 1;
    const u16* kp = Kb + (size_t)idx*512;
    float e0 = 0.f, e1 = 0.f;
#pragma unroll
    for (int d0 = 0; d0 < 64; d0 += 8) {
      short8 k0 = *(const short8*)(kp + h0*64 + d0);
      short8 k1 = *(const short8*)(kp + h1*64 + d0);
#pragma unroll
      for (int i = 0; i < 8; ++i) {
        e0 = fmaf(q_s[h0*64 + d0 + i], bf2f((u16)k0[i]), e0);
        e1 = fmaf(q_s[h1*64 + d0 + i], bf2f((u16)k1[i]), e1);
      }
    }
#pragma unroll
    for (int hh = 0; hh < 2; ++hh) {
      float e = hh ? e1 : e0;
      float m = e;
      m = fmaxf(m, __shfl_xor(m, 1));  m = fmaxf(m, __shfl_xor(m, 2));
      m = fmaxf(m, __shfl_xor(m, 4));  m = fmaxf(m, __shfl_xor(m, 8));
      m = fmaxf(m, __shfl_xor(m, 16)); m = fmaxf(m, __shfl_xor(m, 32));
      float p = __expf(e - m);
      float s = p;
      s += __shfl_xor(s, 1);  s += __shfl_xor(s, 2);  s += __shfl_xor(s, 4);
      s += __shfl_xor(s, 8);  s += __shfl_xor(s, 16); s += __shfl_xor(s, 32);
      att_s[(h0 + hh)*64 + lane] = p / (s * SCALE);
    }
  } else {
    // 128 energies (8h x 16j), 2 threads per energy (32 dims each)
    int h  = w*2 + (lane >> 5);
    int j  = lane & 15;
    int dh = (lane >> 4) & 1;
    int idx = idx_s[j];
    const u16*   kp = Kb + (size_t)idx*512 + h*64 + dh*32;
    const float* qp = q_s + h*64 + dh*32;
    float e = 0.f;
#pragma unroll
    for (int d0 = 0; d0 < 32; d0 += 8) {
      short8 kk = *(const short8*)(kp + d0);
#pragma unroll
      for (int i = 0; i < 8; ++i)
        e = fmaf(qp[d0 + i], bf2f((u16)kk[i]), e);
    }
    e += __shfl_xor(e, 16);
    float m = e;
    m = fmaxf(m, __shfl_xor(m, 1)); m = fmaxf(m, __shfl_xor(m, 2));
    m = fmaxf(m, __shfl_xor(m, 4)); m = fmaxf(m, __shfl_xor(m, 8));
    float p = __expf(e - m);
    float s = p;
    s += __shfl_xor(s, 1); s += __shfl_xor(s, 2);
    s += __shfl_xor(s, 4); s += __shfl_xor(s, 8);
    att_s[h*16 + j] = p / (s * SCALE);
  }
  __syncthreads();

#pragma unroll
  for (int hh = 0; hh < 2; ++hh) {
    int h = w*2 + hh;
    const u16* vbp = Vb + h*64 + lane;
    float a0=0.f, a1=0.f, a2=0.f, a3=0.f;
#pragma unroll
    for (int j = 0; j < KLOC; j += 4) {
      a0 = fmaf(att_s[h*KLOC + j + 0], bf2f(vbp[(size_t)idx_s[j + 0]*512]), a0);
      a1 = fmaf(att_s[h*KLOC + j + 1], bf2f(vbp[(size_t)idx_s[j + 1]*512]), a1);
      a2 = fmaf(att_s[h*KLOC + j + 2], bf2f(vbp[(size_t)idx_s[j + 2]*512]), a2);
      a3 = fmaf(att_s[h*KLOC + j + 3], bf2f(vbp[(size_t)idx_s[j + 3]*512]), a3);
    }
    o_s[h*64 + lane] = (a0 + a1) + (a2 + a3);
  }
  __syncthreads();

  float x0 = o_s[t]       + __builtin_nontemporal_load(resid + (size_t)n*512 + t);
  float x1 = o_s[t + 256] + __builtin_nontemporal_load(resid + (size_t)n*512 + t + 256);
  float s  = x0 + x1, ss = x0*x0 + x1*x1;
  s += __shfl_xor(s, 1);  ss += __shfl_xor(ss, 1);
  s += __shfl_xor(s, 2);  ss += __shfl_xor(ss, 2);
  s += __shfl_xor(s, 4);  ss += __shfl_xor(ss, 4);
  s += __shfl_xor(s, 8);  ss += __shfl_xor(ss, 8);
  s += __shfl_xor(s, 16); ss += __shfl_xor(ss, 16);
  s += __shfl_xor(s, 32); ss += __shfl_xor(ss, 32);
  if (lane == 0) { red_s[w] = s; red_s[4 + w] = ss; }
  __syncthreads();
  float tot  = red_s[0] + red_s[1] + red_s[2] + red_s[3];
  float tots = red_s[4] + red_s[5] + red_s[6] + red_s[7];
  float mean = tot  * (1.0f/512.0f);
  float var  = tots * (1.0f/512.0f) - mean*mean;
  float rstd = rsqrtf(var + LNEPS);
  float y0 = (x0 - mean)*rstd*gma[t]       + bta[t];
  float y1 = (x1 - mean)*rstd*gma[t + 256] + bta[t + 256];
  __builtin_nontemporal_store(y0, outp + (size_t)n*512 + t);
  __builtin_nontemporal_store(y1, outp + (size_t)n*512 + t + 256);
  if (outb != nullptr) {
    outb[(size_t)n*512 + t]       = (u16)f2bf(y0);
    outb[(size_t)n*512 + t + 256] = (u16)f2bf(y1);
  }
  if (attOut != nullptr && t == 0) attOut[n] = 8.0f / SCALE;
}

extern "C" void kernel_launch(void* const* d_in, const int* in_sizes, int n_in,
                              void* d_out, int out_size, void* d_ws, size_t ws_size,
                              hipStream_t stream)
{
  const float* x   = (const float*)d_in[0];
  const int*   A   = (const int*)  d_in[1];
  const float* Wfc = (const float*)d_in[2];
  const float* bfc = (const float*)d_in[3];
  const float* Wq1 = (const float*)d_in[4];
  const float* bq1 = (const float*)d_in[5];
  const float* Wk1 = (const float*)d_in[6];
  const float* bk1 = (const float*)d_in[7];
  const float* Wv1 = (const float*)d_in[8];
  const float* bv1 = (const float*)d_in[9];
  const float* g1  = (const float*)d_in[10];
  const float* be1 = (const float*)d_in[11];
  const float* Wq2 = (const float*)d_in[12];
  const float* bq2 = (const float*)d_in[13];
  const float* Wk2 = (const float*)d_in[14];
  const float* bk2 = (const float*)d_in[15];
  const float* Wv2 = (const float*)d_in[16];
  const float* bv2 = (const float*)d_in[17];
  const float* g2  = (const float*)d_in[18];
  const float* be2 = (const float*)d_in[19];

  char* ws = (char*)d_ws;
  const size_t SZ = (size_t)2048*512;
  // f32 buffers
  float* embs = (float*)ws;                    ws += SZ*4;
  float* b1   = (float*)ws;                    ws += SZ*4;
  // bf16 activation buffers
  u16* embs_b = (u16*)ws;                      ws += SZ*2;
  u16* b1_b   = (u16*)ws;                      ws += SZ*2;
  u16* qb     = (u16*)ws;                      ws += SZ*2;
  u16* kb     = (u16*)ws;                      ws += SZ*2;
  u16* vb     = (u16*)ws;                      ws += SZ*2;
  u16* xb     = (u16*)ws;                      ws += (size_t)2048*1024*2;
  // bf16 transposed weights
  u16* t_fc   = (u16*)ws;                      ws += (size_t)512*1024*2;
  u16* t_q1   = (u16*)ws;                      ws += (size_t)512*512*2;
  u16* t_k1   = (u16*)ws;                      ws += (size_t)512*512*2;
  u16* t_v1   = (u16*)ws;                      ws += (size_t)512*512*2;
  u16* t_q2   = (u16*)ws;                      ws += (size_t)512*512*2;
  u16* t_k2   = (u16*)ws;                      ws += (size_t)512*512*2;
  u16* t_v2   = (u16*)ws;                      ws += (size_t)512*512*2;

  float* out  = (float*)d_out;
  float* att2 = out + SZ;

  dim3 blk(256);
  // prep: x -> bf16 ; weights -> transposed bf16
  cvt_k<<<dim3(2048), blk, 0, stream>>>(x, xb, 2048*1024);
  tr_k<<<dim3(16, 32, 1), blk, 0, stream>>>(Wfc, Wfc, Wfc, Wfc, Wfc, Wfc,
      t_fc, t_fc, t_fc, t_fc, t_fc, t_fc, 1024, 512);
  tr_k<<<dim3(16, 16, 6), blk, 0, stream>>>(Wq1, Wk1, Wv1, Wq2, Wk2, Wv2,
      t_q1, t_k1, t_v1, t_q2, t_k2, t_v2, 512, 512);

  // embs = relu(x @ W_fc + b_fc)   (f32 + bf16)
  gemm_k<true,false><<<dim3(32, 8), blk, 0, stream>>>(xb, 1024,
      t_fc, nullptr, nullptr, bfc, nullptr, nullptr, embs, embs_b, nullptr, nullptr);
  // q/k/v (bf16) = embs @ Wq1/Wk1/Wv1 + b
  gemm_k<false,true><<<dim3(32, 24), blk, 0, stream>>>(embs_b, 512,
      t_q1, t_k1, t_v1, bq1, bk1, bv1, nullptr, qb, kb, vb);
  // attn1 (16 keys) + residual(embs) + LN -> b1 (f32 + bf16)
  attn_k<16><<<dim3(2048), blk, 0, stream>>>(qb, kb, vb, A, embs, g1, be1, b1, b1_b, nullptr);
  // q/k/v for layer 2
  gemm_k<false,true><<<dim3(32, 24), blk, 0, stream>>>(b1_b, 512,
      t_q2, t_k2, t_v2, bq2, bk2, bv2, nullptr, qb, kb, vb);
  // attn2 (64 keys) + residual(b1) + LN -> b2 (d_out), plus Att2
  attn_k<64><<<dim3(2048), blk, 0, stream>>>(qb, kb, vb, A, b1, g2, be2, out, nullptr, att2);
}

// Round 6
// 188.051 us; speedup vs baseline: 2.2034x; 1.1777x over previous
//
#include <hip/hip_runtime.h>

#define SCALE 22.627416997969522f
#define LNEPS 1e-5f

using short8 = __attribute__((ext_vector_type(8))) short;
using f32x4  = __attribute__((ext_vector_type(4))) float;
typedef unsigned short u16;
using u16x4 = __attribute__((ext_vector_type(4))) u16;

static __device__ __forceinline__ short f2bf(float f){
  unsigned u = __builtin_bit_cast(unsigned, f);
  u += 0x7FFFu + ((u >> 16) & 1u);
  return (short)(u >> 16);
}
static __device__ __forceinline__ float bf2f(u16 u){
  unsigned v = ((unsigned)u) << 16;
  return __builtin_bit_cast(float, v);
}

// ---- prep: plain f32 -> bf16 convert (vectorized), n multiple of 1024 ----
__global__ __launch_bounds__(256) void cvt_k(const float* __restrict__ src,
                                             u16* __restrict__ dst, int n)
{
  int i = (blockIdx.x * 256 + threadIdx.x) * 4;
  if (i >= n) return;
  float4 v = *(const float4*)(src + i);
  u16x4 o;
  o[0] = (u16)f2bf(v.x); o[1] = (u16)f2bf(v.y);
  o[2] = (u16)f2bf(v.z); o[3] = (u16)f2bf(v.w);
  *(u16x4*)(dst + i) = o;
}

// ---- prep: W [K][N] f32  ->  Wt [N][K] bf16, LDS-tiled transpose ----
__global__ __launch_bounds__(256) void tr_k(
    const float* __restrict__ W0, const float* __restrict__ W1,
    const float* __restrict__ W2, const float* __restrict__ W3,
    const float* __restrict__ W4, const float* __restrict__ W5,
    u16* __restrict__ T0, u16* __restrict__ T1, u16* __restrict__ T2,
    u16* __restrict__ T3, u16* __restrict__ T4, u16* __restrict__ T5,
    int K, int N)
{
  int z = blockIdx.z;
  const float* W = (z==0)?W0:(z==1)?W1:(z==2)?W2:(z==3)?W3:(z==4)?W4:W5;
  u16*         T = (z==0)?T0:(z==1)?T1:(z==2)?T2:(z==3)?T3:(z==4)?T4:T5;

  __shared__ float tile[32][33];
  int n0 = blockIdx.x * 32, k0 = blockIdx.y * 32;
  int tx = threadIdx.x & 31, ty = threadIdx.x >> 5;  // 32 x 8
#pragma unroll
  for (int i = 0; i < 32; i += 8)
    tile[ty + i][tx] = W[(size_t)(k0 + ty + i) * N + n0 + tx];
  __syncthreads();
#pragma unroll
  for (int i = 0; i < 32; i += 8)
    T[(size_t)(n0 + ty + i) * K + k0 + tx] = (u16)f2bf(tile[tx][ty + i]);
}

// ---- GEMM: C = act(A_bf16[MxK] @ Wt_bf16[N][K]^T + bias) ----
// LDS-staged 64x64 tile, BK=64, reg-prefetch, XOR-swizzled LDS layout.
template<bool RELU, bool SPLIT3>
__global__ __launch_bounds__(256) void gemm_k(
    const u16* __restrict__ A, int K,
    const u16* __restrict__ T0, const u16* __restrict__ T1, const u16* __restrict__ T2,
    const float* __restrict__ B0, const float* __restrict__ B1, const float* __restrict__ B2,
    float* __restrict__ C0f, u16* __restrict__ C0b,
    u16* __restrict__ C1, u16* __restrict__ C2)
{
  __shared__ u16 As[64*64];   // 8 KB, row = 128B, slot-swizzled
  __shared__ u16 Bs[64*64];

  int bm = blockIdx.x;
  int nglob = blockIdx.y * 64;
  int sel  = SPLIT3 ? (nglob >> 9) : 0;
  int ncol = nglob & 511;
  const u16*   T  = (sel==0) ? T0 : (sel==1) ? T1 : T2;
  const float* Bv = (sel==0) ? B0 : (sel==1) ? B1 : B2;

  int t = threadIdx.x;
  int wave = t >> 6, lane = t & 63;
  int wm = (wave >> 1) * 32, wn = (wave & 1) * 32;
  int lr = lane & 15, kg = lane >> 4;

  int o0 = t*16, o1 = 4096 + t*16;
  int r0 = o0 >> 7, cb0 = o0 & 127;
  int r1 = o1 >> 7, cb1 = o1 & 127;
  const char* Ag0 = (const char*)(A + (size_t)(bm*64 + r0) * K) + cb0;
  const char* Ag1 = (const char*)(A + (size_t)(bm*64 + r1) * K) + cb1;
  const char* Bg0 = (const char*)(T + (size_t)(ncol  + r0) * K) + cb0;
  const char* Bg1 = (const char*)(T + (size_t)(ncol  + r1) * K) + cb1;
  char* Ad0 = (char*)As + r0*128 + (cb0 ^ ((r0 & 7) << 4));
  char* Ad1 = (char*)As + r1*128 + (cb1 ^ ((r1 & 7) << 4));
  char* Bd0 = (char*)Bs + r0*128 + (cb0 ^ ((r0 & 7) << 4));
  char* Bd1 = (char*)Bs + r1*128 + (cb1 ^ ((r1 & 7) << 4));

  int sw = (lr & 7) << 4;
  const char* Afr0 = (const char*)As + (wm + lr) * 128;
  const char* Afr1 = (const char*)As + (wm + 16 + lr) * 128;
  const char* Bfr0 = (const char*)Bs + (wn + lr) * 128;
  const char* Bfr1 = (const char*)Bs + (wn + 16 + lr) * 128;

  f32x4 acc[2][2] = {};

  short8 pa0 = *(const short8*)Ag0;
  short8 pa1 = *(const short8*)Ag1;
  short8 pb0 = *(const short8*)Bg0;
  short8 pb1 = *(const short8*)Bg1;

  for (int k0 = 0; k0 < K; k0 += 64) {
    __syncthreads();
    *(short8*)Ad0 = pa0;  *(short8*)Ad1 = pa1;
    *(short8*)Bd0 = pb0;  *(short8*)Bd1 = pb1;
    __syncthreads();
    int kn = k0 + 64;
    if (kn < K) {
      pa0 = *(const short8*)(Ag0 + kn*2);
      pa1 = *(const short8*)(Ag1 + kn*2);
      pb0 = *(const short8*)(Bg0 + kn*2);
      pb1 = *(const short8*)(Bg1 + kn*2);
    }
#pragma unroll
    for (int ks = 0; ks < 2; ++ks) {
      int cb = (ks*64 + kg*16) ^ sw;
      short8 af0 = *(const short8*)(Afr0 + cb);
      short8 af1 = *(const short8*)(Afr1 + cb);
      short8 bf0 = *(const short8*)(Bfr0 + cb);
      short8 bf1 = *(const short8*)(Bfr1 + cb);
      acc[0][0] = __builtin_amdgcn_mfma_f32_16x16x32_bf16(af0, bf0, acc[0][0], 0, 0, 0);
      acc[0][1] = __builtin_amdgcn_mfma_f32_16x16x32_bf16(af0, bf1, acc[0][1], 0, 0, 0);
      acc[1][0] = __builtin_amdgcn_mfma_f32_16x16x32_bf16(af1, bf0, acc[1][0], 0, 0, 0);
      acc[1][1] = __builtin_amdgcn_mfma_f32_16x16x32_bf16(af1, bf1, acc[1][1], 0, 0, 0);
    }
  }

#pragma unroll
  for (int mi = 0; mi < 2; ++mi)
#pragma unroll
    for (int ni = 0; ni < 2; ++ni) {
      int col = ncol + wn + ni*16 + lr;
      float bia = Bv[col];
#pragma unroll
      for (int r = 0; r < 4; ++r) {
        int row = bm*64 + wm + mi*16 + kg*4 + r;
        float vv = acc[mi][ni][r] + bia;
        if (RELU) vv = fmaxf(vv, 0.f);
        if (SPLIT3) {
          u16* C = (sel==0) ? C0b : (sel==1) ? C1 : C2;
          C[(size_t)row*512 + col] = (u16)f2bf(vv);
        } else {
          C0f[(size_t)row*512 + col] = vv;
          C0b[(size_t)row*512 + col] = (u16)f2bf(vv);
        }
      }
    }
}

// One block (4 waves) per token.
template<int KLOC>
__global__ __launch_bounds__(256) void attn_k(
    const u16* __restrict__ Qb, const u16* __restrict__ Kb, const u16* __restrict__ Vb,
    const int* __restrict__ Aidx,
    const float* __restrict__ resid,
    const float* __restrict__ gma, const float* __restrict__ bta,
    float* __restrict__ outp, u16* __restrict__ outb, float* __restrict__ attOut)
{
  __shared__ float q_s[512];
  __shared__ float att_s[8*KLOC];
  __shared__ float o_s[512];
  __shared__ int   idx_s[KLOC];
  __shared__ float red_s[8];

  int n = blockIdx.x;
  int t = threadIdx.x, w = t >> 6, lane = t & 63;

  q_s[t]       = bf2f(Qb[(size_t)n*512 + t]);
  q_s[t + 256] = bf2f(Qb[(size_t)n*512 + t + 256]);
  if (t < KLOC) idx_s[t] = Aidx[(size_t)n*64 + t];
  __syncthreads();

  if (KLOC == 64) {
    int idx = idx_s[lane];
    int h0 = w*2, h1 = h0 + 1;
    const u16* kp = Kb + (size_t)idx*512;
    float e0 = 0.f, e1 = 0.f;
#pragma unroll
    for (int d0 = 0; d0 < 64; d0 += 8) {
      short8 k0 = *(const short8*)(kp + h0*64 + d0);
      short8 k1 = *(const short8*)(kp + h1*64 + d0);
#pragma unroll
      for (int i = 0; i < 8; ++i) {
        e0 = fmaf(q_s[h0*64 + d0 + i], bf2f((u16)k0[i]), e0);
        e1 = fmaf(q_s[h1*64 + d0 + i], bf2f((u16)k1[i]), e1);
      }
    }
#pragma unroll
    for (int hh = 0; hh < 2; ++hh) {
      float e = hh ? e1 : e0;
      float m = e;
      m = fmaxf(m, __shfl_xor(m, 1));  m = fmaxf(m, __shfl_xor(m, 2));
      m = fmaxf(m, __shfl_xor(m, 4));  m = fmaxf(m, __shfl_xor(m, 8));
      m = fmaxf(m, __shfl_xor(m, 16)); m = fmaxf(m, __shfl_xor(m, 32));
      float p = __expf(e - m);
      float s = p;
      s += __shfl_xor(s, 1);  s += __shfl_xor(s, 2);  s += __shfl_xor(s, 4);
      s += __shfl_xor(s, 8);  s += __shfl_xor(s, 16); s += __shfl_xor(s, 32);
      att_s[(h0 + hh)*64 + lane] = p / (s * SCALE);
    }
  } else {
    int h  = w*2 + (lane >> 5);
    int j  = lane & 15;
    int dh = (lane >> 4) & 1;
    int idx = idx_s[j];
    const u16*   kp = Kb + (size_t)idx*512 + h*64 + dh*32;
    const float* qp = q_s + h*64 + dh*32;
    float e = 0.f;
#pragma unroll
    for (int d0 = 0; d0 < 32; d0 += 8) {
      short8 kk = *(const short8*)(kp + d0);
#pragma unroll
      for (int i = 0; i < 8; ++i)
        e = fmaf(qp[d0 + i], bf2f((u16)kk[i]), e);
    }
    e += __shfl_xor(e, 16);
    float m = e;
    m = fmaxf(m, __shfl_xor(m, 1)); m = fmaxf(m, __shfl_xor(m, 2));
    m = fmaxf(m, __shfl_xor(m, 4)); m = fmaxf(m, __shfl_xor(m, 8));
    float p = __expf(e - m);
    float s = p;
    s += __shfl_xor(s, 1); s += __shfl_xor(s, 2);
    s += __shfl_xor(s, 4); s += __shfl_xor(s, 8);
    att_s[h*16 + j] = p / (s * SCALE);
  }
  __syncthreads();

  {
    int jg = lane >> 3, dc = lane & 7;
#pragma unroll
    for (int hh = 0; hh < 2; ++hh) {
      int h = w*2 + hh;
      float vacc[8] = {0.f,0.f,0.f,0.f,0.f,0.f,0.f,0.f};
#pragma unroll
      for (int jb = 0; jb < KLOC; jb += 8) {
        int j = jb + jg;
        const u16* vp = Vb + (size_t)idx_s[j]*512 + h*64 + dc*8;
        short8 vv = *(const short8*)vp;
        float a = att_s[h*KLOC + j];
#pragma unroll
        for (int i = 0; i < 8; ++i)
          vacc[i] = fmaf(a, bf2f((u16)vv[i]), vacc[i]);
      }
#pragma unroll
      for (int i = 0; i < 8; ++i) {
        vacc[i] += __shfl_xor(vacc[i], 8);
        vacc[i] += __shfl_xor(vacc[i], 16);
        vacc[i] += __shfl_xor(vacc[i], 32);
      }
      if (jg == 0) {
#pragma unroll
        for (int i = 0; i < 8; ++i)
          o_s[h*64 + dc*8 + i] = vacc[i];
      }
    }
  }
  __syncthreads();

  float x0 = o_s[t]       + __builtin_nontemporal_load(resid + (size_t)n*512 + t);
  float x1 = o_s[t + 256] + __builtin_nontemporal_load(resid + (size_t)n*512 + t + 256);
  float s  = x0 + x1, ss = x0*x0 + x1*x1;
  s += __shfl_xor(s, 1);  ss += __shfl_xor(ss, 1);
  s += __shfl_xor(s, 2);  ss += __shfl_xor(ss, 2);
  s += __shfl_xor(s, 4);  ss += __shfl_xor(ss, 4);
  s += __shfl_xor(s, 8);  ss += __shfl_xor(ss, 8);
  s += __shfl_xor(s, 16); ss += __shfl_xor(ss, 16);
  s += __shfl_xor(s, 32); ss += __shfl_xor(ss, 32);
  if (lane == 0) { red_s[w] = s; red_s[4 + w] = ss; }
  __syncthreads();
  float tot  = red_s[0] + red_s[1] + red_s[2] + red_s[3];
  float tots = red_s[4] + red_s[5] + red_s[6] + red_s[7];
  float mean = tot  * (1.0f/512.0f);
  float var  = tots * (1.0f/512.0f) - mean*mean;
  float rstd = rsqrtf(var + LNEPS);
  float y0 = (x0 - mean)*rstd*gma[t]       + bta[t];
  float y1 = (x1 - mean)*rstd*gma[t + 256] + bta[t + 256];
  __builtin_nontemporal_store(y0, outp + (size_t)n*512 + t);
  __builtin_nontemporal_store(y1, outp + (size_t)n*512 + t + 256);
  if (outb != nullptr) {
    outb[(size_t)n*512 + t]       = (u16)f2bf(y0);
    outb[(size_t)n*512 + t + 256] = (u16)f2bf(y1);
  }
  if (attOut != nullptr && t == 0) attOut[n] = 8.0f / SCALE;
}

extern "C" void kernel_launch(void* const* d_in, const int* in_sizes, int n_in,
                              void* d_out, int out_size, void* d_ws, size_t ws_size,
                              hipStream_t stream)
{
  const float* x   = (const float*)d_in[0];
  const int*   A   = (const int*)  d_in[1];
  const float* Wfc = (const float*)d_in[2];
  const float* bfc = (const float*)d_in[3];
  const float* Wq1 = (const float*)d_in[4];
  const float* bq1 = (const float*)d_in[5];
  const float* Wk1 = (const float*)d_in[6];
  const float* bk1 = (const float*)d_in[7];
  const float* Wv1 = (const float*)d_in[8];
  const float* bv1 = (const float*)d_in[9];
  const float* g1  = (const float*)d_in[10];
  const float* be1 = (const float*)d_in[11];
  const float* Wq2 = (const float*)d_in[12];
  const float* bq2 = (const float*)d_in[13];
  const float* Wk2 = (const float*)d_in[14];
  const float* bk2 = (const float*)d_in[15];
  const float* Wv2 = (const float*)d_in[16];
  const float* bv2 = (const float*)d_in[17];
  const float* g2  = (const float*)d_in[18];
  const float* be2 = (const float*)d_in[19];

  char* ws = (char*)d_ws;
  const size_t SZ = (size_t)2048*512;
  float* embs = (float*)ws;                    ws += SZ*4;
  float* b1   = (float*)ws;                    ws += SZ*4;
  u16* embs_b = (u16*)ws;                      ws += SZ*2;
  u16* b1_b   = (u16*)ws;                      ws += SZ*2;
  u16* qb     = (u16*)ws;                      ws += SZ*2;
  u16* kb     = (u16*)ws;                      ws += SZ*2;
  u16* vb     = (u16*)ws;                      ws += SZ*2;
  u16* xb     = (u16*)ws;                      ws += (size_t)2048*1024*2;
  u16* t_fc   = (u16*)ws;                      ws += (size_t)512*1024*2;
  u16* t_q1   = (u16*)ws;                      ws += (size_t)512*512*2;
  u16* t_k1   = (u16*)ws;                      ws += (size_t)512*512*2;
  u16* t_v1   = (u16*)ws;                      ws += (size_t)512*512*2;
  u16* t_q2   = (u16*)ws;                      ws += (size_t)512*512*2;
  u16* t_k2   = (u16*)ws;                      ws += (size_t)512*512*2;
  u16* t_v2   = (u16*)ws;                      ws += (size_t)512*512*2;

  float* out  = (float*)d_out;
  float* att2 = out + SZ;

  dim3 blk(256);
  cvt_k<<<dim3(2048), blk, 0, stream>>>(x, xb, 2048*1024);
  tr_k<<<dim3(16, 32, 1), blk, 0, stream>>>(Wfc, Wfc, Wfc, Wfc, Wfc, Wfc,
      t_fc, t_fc, t_fc, t_fc, t_fc, t_fc, 1024, 512);
  tr_k<<<dim3(16, 16, 6), blk, 0, stream>>>(Wq1, Wk1, Wv1, Wq2, Wk2, Wv2,
      t_q1, t_k1, t_v1, t_q2, t_k2, t_v2, 512, 512);

  gemm_k<true,false><<<dim3(32, 8), blk, 0, stream>>>(xb, 1024,
      t_fc, nullptr, nullptr, bfc, nullptr, nullptr, embs, embs_b, nullptr, nullptr);
  gemm_k<false,true><<<dim3(32, 24), blk, 0, stream>>>(embs_b, 512,
      t_q1, t_k1, t_v1, bq1, bk1, bv1, nullptr, qb, kb, vb);
  attn_k<16><<<dim3(2048), blk, 0, stream>>>(qb, kb, vb, A, embs, g1, be1, b1, b1_b, nullptr);
  gemm_k<false,true><<<dim3(32, 24), blk, 0, stream>>>(b1_b, 512,
      t_q2, t_k2, t_v2, bq2, bk2, bv2, nullptr, qb, kb, vb);
  attn_k<64><<<dim3(2048), blk, 0, stream>>>(qb, kb, vb, A, b1, g2, be2, out, nullptr, att2);
}

// Round 7
// 179.171 us; speedup vs baseline: 2.3126x; 1.0496x over previous
//
#include <hip/hip_runtime.h>

#define SCALE 22.627416997969522f
#define LNEPS 1e-5f

using short8 = __attribute__((ext_vector_type(8))) short;
using f32x4  = __attribute__((ext_vector_type(4))) float;
typedef unsigned short u16;
using u16x4 = __attribute__((ext_vector_type(4))) u16;

static __device__ __forceinline__ short f2bf(float f){
  unsigned u = __builtin_bit_cast(unsigned, f);
  u += 0x7FFFu + ((u >> 16) & 1u);
  return (short)(u >> 16);
}
static __device__ __forceinline__ float bf2f(u16 u){
  unsigned v = ((unsigned)u) << 16;
  return __builtin_bit_cast(float, v);
}

// ---- prep: plain f32 -> bf16 convert (vectorized) ----
__global__ __launch_bounds__(256) void cvt_k(const float* __restrict__ src,
                                             u16* __restrict__ dst, int n)
{
  int i = (blockIdx.x * 256 + threadIdx.x) * 4;
  if (i >= n) return;
  float4 v = *(const float4*)(src + i);
  u16x4 o;
  o[0] = (u16)f2bf(v.x); o[1] = (u16)f2bf(v.y);
  o[2] = (u16)f2bf(v.z); o[3] = (u16)f2bf(v.w);
  *(u16x4*)(dst + i) = o;
}

// ---- prep: W [K][N] f32  ->  Wt [N][K] bf16, LDS-tiled transpose ----
__global__ __launch_bounds__(256) void tr_k(
    const float* __restrict__ W0, const float* __restrict__ W1,
    const float* __restrict__ W2, const float* __restrict__ W3,
    const float* __restrict__ W4, const float* __restrict__ W5,
    u16* __restrict__ T0, u16* __restrict__ T1, u16* __restrict__ T2,
    u16* __restrict__ T3, u16* __restrict__ T4, u16* __restrict__ T5,
    int K, int N)
{
  int z = blockIdx.z;
  const float* W = (z==0)?W0:(z==1)?W1:(z==2)?W2:(z==3)?W3:(z==4)?W4:W5;
  u16*         T = (z==0)?T0:(z==1)?T1:(z==2)?T2:(z==3)?T3:(z==4)?T4:T5;

  __shared__ float tile[32][33];
  int n0 = blockIdx.x * 32, k0 = blockIdx.y * 32;
  int tx = threadIdx.x & 31, ty = threadIdx.x >> 5;  // 32 x 8
#pragma unroll
  for (int i = 0; i < 32; i += 8)
    tile[ty + i][tx] = W[(size_t)(k0 + ty + i) * N + n0 + tx];
  __syncthreads();
#pragma unroll
  for (int i = 0; i < 32; i += 8)
    T[(size_t)(n0 + ty + i) * K + k0 + tx] = (u16)f2bf(tile[tx][ty + i]);
}

// ---- GEMM: C = act(A_bf16[MxK] @ Wt_bf16[N][K]^T + bias) ----
// LDS-staged 64x64 tile, BK=64, reg-prefetch, XOR-swizzled LDS layout.
template<bool RELU, bool SPLIT3>
__global__ __launch_bounds__(256) void gemm_k(
    const u16* __restrict__ A, int K,
    const u16* __restrict__ T0, const u16* __restrict__ T1, const u16* __restrict__ T2,
    const float* __restrict__ B0, const float* __restrict__ B1, const float* __restrict__ B2,
    float* __restrict__ C0f, u16* __restrict__ C0b,
    u16* __restrict__ C1, u16* __restrict__ C2)
{
  __shared__ u16 As[64*64];
  __shared__ u16 Bs[64*64];

  int bm = blockIdx.x;
  int nglob = blockIdx.y * 64;
  int sel  = SPLIT3 ? (nglob >> 9) : 0;
  int ncol = nglob & 511;
  const u16*   T  = (sel==0) ? T0 : (sel==1) ? T1 : T2;
  const float* Bv = (sel==0) ? B0 : (sel==1) ? B1 : B2;

  int t = threadIdx.x;
  int wave = t >> 6, lane = t & 63;
  int wm = (wave >> 1) * 32, wn = (wave & 1) * 32;
  int lr = lane & 15, kg = lane >> 4;

  int o0 = t*16, o1 = 4096 + t*16;
  int r0 = o0 >> 7, cb0 = o0 & 127;
  int r1 = o1 >> 7, cb1 = o1 & 127;
  const char* Ag0 = (const char*)(A + (size_t)(bm*64 + r0) * K) + cb0;
  const char* Ag1 = (const char*)(A + (size_t)(bm*64 + r1) * K) + cb1;
  const char* Bg0 = (const char*)(T + (size_t)(ncol  + r0) * K) + cb0;
  const char* Bg1 = (const char*)(T + (size_t)(ncol  + r1) * K) + cb1;
  char* Ad0 = (char*)As + r0*128 + (cb0 ^ ((r0 & 7) << 4));
  char* Ad1 = (char*)As + r1*128 + (cb1 ^ ((r1 & 7) << 4));
  char* Bd0 = (char*)Bs + r0*128 + (cb0 ^ ((r0 & 7) << 4));
  char* Bd1 = (char*)Bs + r1*128 + (cb1 ^ ((r1 & 7) << 4));

  int sw = (lr & 7) << 4;
  const char* Afr0 = (const char*)As + (wm + lr) * 128;
  const char* Afr1 = (const char*)As + (wm + 16 + lr) * 128;
  const char* Bfr0 = (const char*)Bs + (wn + lr) * 128;
  const char* Bfr1 = (const char*)Bs + (wn + 16 + lr) * 128;

  f32x4 acc[2][2] = {};

  short8 pa0 = *(const short8*)Ag0;
  short8 pa1 = *(const short8*)Ag1;
  short8 pb0 = *(const short8*)Bg0;
  short8 pb1 = *(const short8*)Bg1;

  for (int k0 = 0; k0 < K; k0 += 64) {
    __syncthreads();
    *(short8*)Ad0 = pa0;  *(short8*)Ad1 = pa1;
    *(short8*)Bd0 = pb0;  *(short8*)Bd1 = pb1;
    __syncthreads();
    int kn = k0 + 64;
    if (kn < K) {
      pa0 = *(const short8*)(Ag0 + kn*2);
      pa1 = *(const short8*)(Ag1 + kn*2);
      pb0 = *(const short8*)(Bg0 + kn*2);
      pb1 = *(const short8*)(Bg1 + kn*2);
    }
#pragma unroll
    for (int ks = 0; ks < 2; ++ks) {
      int cb = (ks*64 + kg*16) ^ sw;
      short8 af0 = *(const short8*)(Afr0 + cb);
      short8 af1 = *(const short8*)(Afr1 + cb);
      short8 bf0 = *(const short8*)(Bfr0 + cb);
      short8 bf1 = *(const short8*)(Bfr1 + cb);
      acc[0][0] = __builtin_amdgcn_mfma_f32_16x16x32_bf16(af0, bf0, acc[0][0], 0, 0, 0);
      acc[0][1] = __builtin_amdgcn_mfma_f32_16x16x32_bf16(af0, bf1, acc[0][1], 0, 0, 0);
      acc[1][0] = __builtin_amdgcn_mfma_f32_16x16x32_bf16(af1, bf0, acc[1][0], 0, 0, 0);
      acc[1][1] = __builtin_amdgcn_mfma_f32_16x16x32_bf16(af1, bf1, acc[1][1], 0, 0, 0);
    }
  }

#pragma unroll
  for (int mi = 0; mi < 2; ++mi)
#pragma unroll
    for (int ni = 0; ni < 2; ++ni) {
      int col = ncol + wn + ni*16 + lr;
      float bia = Bv[col];
#pragma unroll
      for (int r = 0; r < 4; ++r) {
        int row = bm*64 + wm + mi*16 + kg*4 + r;
        float vv = acc[mi][ni][r] + bia;
        if (RELU) vv = fmaxf(vv, 0.f);
        if (SPLIT3) {
          u16* C = (sel==0) ? C0b : (sel==1) ? C1 : C2;
          C[(size_t)row*512 + col] = (u16)f2bf(vv);
        } else {
          C0f[(size_t)row*512 + col] = vv;
          C0b[(size_t)row*512 + col] = (u16)f2bf(vv);
        }
      }
    }
}

// One block (4 waves) per token. K/V rows staged COALESCED into LDS
// (time-shared buffer), XOR-swizzled; energies + PV read from LDS.
template<int KLOC>
__global__ __launch_bounds__(256) void attn_k(
    const u16* __restrict__ Qb, const u16* __restrict__ Kb, const u16* __restrict__ Vb,
    const int* __restrict__ Aidx,
    const float* __restrict__ resid,
    const float* __restrict__ gma, const float* __restrict__ bta,
    float* __restrict__ outp, u16* __restrict__ outb, float* __restrict__ attOut)
{
  __shared__ u16   kv_s[KLOC*512];   // K then V; row = 1KB, 16B-slot swizzled
  __shared__ float q_s[512];
  __shared__ float att_s[8*KLOC];
  __shared__ float o_s[512];
  __shared__ int   idx_s[KLOC];
  __shared__ float red_s[8];

  int n = blockIdx.x;
  int t = threadIdx.x, w = t >> 6, lane = t & 63;

  {
    ushort2 qv = *(const ushort2*)(Qb + (size_t)n*512 + 2*t);
    q_s[2*t]   = bf2f(qv.x);
    q_s[2*t+1] = bf2f(qv.y);
  }
  if (t < KLOC) idx_s[t] = Aidx[(size_t)n*64 + t];
  __syncthreads();

  // ---- stage K rows, coalesced: one wave-instr per 1KB row ----
  constexpr int RPW = KLOC/4;
#pragma unroll
  for (int jj = 0; jj < RPW; ++jj) {
    int j = w*RPW + jj;
    short8 vv = ((const short8*)(Kb + (size_t)idx_s[j]*512))[lane];
    *(short8*)((char*)kv_s + j*1024 + ((lane*16) ^ ((j&7)<<4))) = vv;
  }
  __syncthreads();

  // ---- energies from LDS ----
  if (KLOC == 64) {
    int j = lane;
    const char* kp = (const char*)kv_s + j*1024;
    int swz = (j&7) << 4;
    int h0 = w*2, h1 = h0 + 1;
    float e0 = 0.f, e1 = 0.f;
#pragma unroll
    for (int c = 0; c < 8; ++c) {
      short8 k0 = *(const short8*)(kp + ((h0*128 + c*16) ^ swz));
      short8 k1 = *(const short8*)(kp + ((h1*128 + c*16) ^ swz));
#pragma unroll
      for (int i = 0; i < 8; ++i) {
        e0 = fmaf(q_s[h0*64 + c*8 + i], bf2f((u16)k0[i]), e0);
        e1 = fmaf(q_s[h1*64 + c*8 + i], bf2f((u16)k1[i]), e1);
      }
    }
#pragma unroll
    for (int hh = 0; hh < 2; ++hh) {
      float e = hh ? e1 : e0;
      float m = e;
      m = fmaxf(m, __shfl_xor(m, 1));  m = fmaxf(m, __shfl_xor(m, 2));
      m = fmaxf(m, __shfl_xor(m, 4));  m = fmaxf(m, __shfl_xor(m, 8));
      m = fmaxf(m, __shfl_xor(m, 16)); m = fmaxf(m, __shfl_xor(m, 32));
      float p = __expf(e - m);
      float s = p;
      s += __shfl_xor(s, 1);  s += __shfl_xor(s, 2);  s += __shfl_xor(s, 4);
      s += __shfl_xor(s, 8);  s += __shfl_xor(s, 16); s += __shfl_xor(s, 32);
      att_s[(h0 + hh)*64 + lane] = p / (s * SCALE);
    }
  } else {
    // 128 energies (8h x 16j), 2 threads per energy (32 dims each)
    int h  = w*2 + (lane >> 5);
    int j  = lane & 15;
    int dh = (lane >> 4) & 1;
    const char* kp = (const char*)kv_s + j*1024;
    int swz = (j&7) << 4;
    int base = h*128 + dh*64;
    float e = 0.f;
#pragma unroll
    for (int c = 0; c < 4; ++c) {
      short8 kk = *(const short8*)(kp + ((base + c*16) ^ swz));
#pragma unroll
      for (int i = 0; i < 8; ++i)
        e = fmaf(q_s[h*64 + dh*32 + c*8 + i], bf2f((u16)kk[i]), e);
    }
    e += __shfl_xor(e, 16);
    float m = e;
    m = fmaxf(m, __shfl_xor(m, 1)); m = fmaxf(m, __shfl_xor(m, 2));
    m = fmaxf(m, __shfl_xor(m, 4)); m = fmaxf(m, __shfl_xor(m, 8));
    float p = __expf(e - m);
    float s = p;
    s += __shfl_xor(s, 1); s += __shfl_xor(s, 2);
    s += __shfl_xor(s, 4); s += __shfl_xor(s, 8);
    att_s[h*16 + j] = p / (s * SCALE);
  }
  __syncthreads();   // all K reads + att_s writes done

  // ---- stage V rows into the same buffer ----
#pragma unroll
  for (int jj = 0; jj < RPW; ++jj) {
    int j = w*RPW + jj;
    short8 vv = ((const short8*)(Vb + (size_t)idx_s[j]*512))[lane];
    *(short8*)((char*)kv_s + j*1024 + ((lane*16) ^ ((j&7)<<4))) = vv;
  }
  __syncthreads();

  // ---- PV from LDS: lane = (jg, dc) ----
  {
    int jg = lane >> 3, dc = lane & 7;
#pragma unroll
    for (int hh = 0; hh < 2; ++hh) {
      int h = w*2 + hh;
      float vacc[8] = {0.f,0.f,0.f,0.f,0.f,0.f,0.f,0.f};
#pragma unroll
      for (int jb = 0; jb < KLOC; jb += 8) {
        int r = jb + jg;
        short8 vv = *(const short8*)((char*)kv_s + r*1024 + ((h*128 + dc*16) ^ ((r&7)<<4)));
        float a = att_s[h*KLOC + r];
#pragma unroll
        for (int i = 0; i < 8; ++i)
          vacc[i] = fmaf(a, bf2f((u16)vv[i]), vacc[i]);
      }
#pragma unroll
      for (int i = 0; i < 8; ++i) {
        vacc[i] += __shfl_xor(vacc[i], 8);
        vacc[i] += __shfl_xor(vacc[i], 16);
        vacc[i] += __shfl_xor(vacc[i], 32);
      }
      if (jg == 0) {
#pragma unroll
        for (int i = 0; i < 8; ++i)
          o_s[h*64 + dc*8 + i] = vacc[i];
      }
    }
  }
  __syncthreads();

  // ---- residual + LayerNorm ----
  float x0 = o_s[t]       + __builtin_nontemporal_load(resid + (size_t)n*512 + t);
  float x1 = o_s[t + 256] + __builtin_nontemporal_load(resid + (size_t)n*512 + t + 256);
  float s  = x0 + x1, ss = x0*x0 + x1*x1;
  s += __shfl_xor(s, 1);  ss += __shfl_xor(ss, 1);
  s += __shfl_xor(s, 2);  ss += __shfl_xor(ss, 2);
  s += __shfl_xor(s, 4);  ss += __shfl_xor(ss, 4);
  s += __shfl_xor(s, 8);  ss += __shfl_xor(ss, 8);
  s += __shfl_xor(s, 16); ss += __shfl_xor(ss, 16);
  s += __shfl_xor(s, 32); ss += __shfl_xor(ss, 32);
  if (lane == 0) { red_s[w] = s; red_s[4 + w] = ss; }
  __syncthreads();
  float tot  = red_s[0] + red_s[1] + red_s[2] + red_s[3];
  float tots = red_s[4] + red_s[5] + red_s[6] + red_s[7];
  float mean = tot  * (1.0f/512.0f);
  float var  = tots * (1.0f/512.0f) - mean*mean;
  float rstd = rsqrtf(var + LNEPS);
  float y0 = (x0 - mean)*rstd*gma[t]       + bta[t];
  float y1 = (x1 - mean)*rstd*gma[t + 256] + bta[t + 256];
  __builtin_nontemporal_store(y0, outp + (size_t)n*512 + t);
  __builtin_nontemporal_store(y1, outp + (size_t)n*512 + t + 256);
  if (outb != nullptr) {
    outb[(size_t)n*512 + t]       = (u16)f2bf(y0);
    outb[(size_t)n*512 + t + 256] = (u16)f2bf(y1);
  }
  if (attOut != nullptr && t == 0) attOut[n] = 8.0f / SCALE;
}

extern "C" void kernel_launch(void* const* d_in, const int* in_sizes, int n_in,
                              void* d_out, int out_size, void* d_ws, size_t ws_size,
                              hipStream_t stream)
{
  const float* x   = (const float*)d_in[0];
  const int*   A   = (const int*)  d_in[1];
  const float* Wfc = (const float*)d_in[2];
  const float* bfc = (const float*)d_in[3];
  const float* Wq1 = (const float*)d_in[4];
  const float* bq1 = (const float*)d_in[5];
  const float* Wk1 = (const float*)d_in[6];
  const float* bk1 = (const float*)d_in[7];
  const float* Wv1 = (const float*)d_in[8];
  const float* bv1 = (const float*)d_in[9];
  const float* g1  = (const float*)d_in[10];
  const float* be1 = (const float*)d_in[11];
  const float* Wq2 = (const float*)d_in[12];
  const float* bq2 = (const float*)d_in[13];
  const float* Wk2 = (const float*)d_in[14];
  const float* bk2 = (const float*)d_in[15];
  const float* Wv2 = (const float*)d_in[16];
  const float* bv2 = (const float*)d_in[17];
  const float* g2  = (const float*)d_in[18];
  const float* be2 = (const float*)d_in[19];

  char* ws = (char*)d_ws;
  const size_t SZ = (size_t)2048*512;
  float* embs = (float*)ws;                    ws += SZ*4;
  float* b1   = (float*)ws;                    ws += SZ*4;
  u16* embs_b = (u16*)ws;                      ws += SZ*2;
  u16* b1_b   = (u16*)ws;                      ws += SZ*2;
  u16* qb     = (u16*)ws;                      ws += SZ*2;
  u16* kb     = (u16*)ws;                      ws += SZ*2;
  u16* vb     = (u16*)ws;                      ws += SZ*2;
  u16* xb     = (u16*)ws;                      ws += (size_t)2048*1024*2;
  u16* t_fc   = (u16*)ws;                      ws += (size_t)512*1024*2;
  u16* t_q1   = (u16*)ws;                      ws += (size_t)512*512*2;
  u16* t_k1   = (u16*)ws;                      ws += (size_t)512*512*2;
  u16* t_v1   = (u16*)ws;                      ws += (size_t)512*512*2;
  u16* t_q2   = (u16*)ws;                      ws += (size_t)512*512*2;
  u16* t_k2   = (u16*)ws;                      ws += (size_t)512*512*2;
  u16* t_v2   = (u16*)ws;                      ws += (size_t)512*512*2;

  float* out  = (float*)d_out;
  float* att2 = out + SZ;

  dim3 blk(256);
  cvt_k<<<dim3(2048), blk, 0, stream>>>(x, xb, 2048*1024);
  tr_k<<<dim3(16, 32, 1), blk, 0, stream>>>(Wfc, Wfc, Wfc, Wfc, Wfc, Wfc,
      t_fc, t_fc, t_fc, t_fc, t_fc, t_fc, 1024, 512);
  tr_k<<<dim3(16, 16, 6), blk, 0, stream>>>(Wq1, Wk1, Wv1, Wq2, Wk2, Wv2,
      t_q1, t_k1, t_v1, t_q2, t_k2, t_v2, 512, 512);

  gemm_k<true,false><<<dim3(32, 8), blk, 0, stream>>>(xb, 1024,
      t_fc, nullptr, nullptr, bfc, nullptr, nullptr, embs, embs_b, nullptr, nullptr);
  gemm_k<false,true><<<dim3(32, 24), blk, 0, stream>>>(embs_b, 512,
      t_q1, t_k1, t_v1, bq1, bk1, bv1, nullptr, qb, kb, vb);
  attn_k<16><<<dim3(2048), blk, 0, stream>>>(qb, kb, vb, A, embs, g1, be1, b1, b1_b, nullptr);
  gemm_k<false,true><<<dim3(32, 24), blk, 0, stream>>>(b1_b, 512,
      t_q2, t_k2, t_v2, bq2, bk2, bv2, nullptr, qb, kb, vb);
  attn_k<64><<<dim3(2048), blk, 0, stream>>>(qb, kb, vb, A, b1, g2, be2, out, nullptr, att2);
}

// Round 9
// 174.688 us; speedup vs baseline: 2.3719x; 1.0257x over previous
//
#include <hip/hip_runtime.h>

#define SCALE 22.627416997969522f
#define LNEPS 1e-5f

using short8 = __attribute__((ext_vector_type(8))) short;
using f32x4  = __attribute__((ext_vector_type(4))) float;
typedef unsigned short u16;
using u16x4 = __attribute__((ext_vector_type(4))) u16;

static __device__ __forceinline__ short f2bf(float f){
  unsigned u = __builtin_bit_cast(unsigned, f);
  u += 0x7FFFu + ((u >> 16) & 1u);
  return (short)(u >> 16);
}
static __device__ __forceinline__ float bf2f(u16 u){
  unsigned v = ((unsigned)u) << 16;
  return __builtin_bit_cast(float, v);
}

// ---- prep: plain f32 -> bf16 convert (vectorized) ----
__global__ __launch_bounds__(256) void cvt_k(const float* __restrict__ src,
                                             u16* __restrict__ dst, int n)
{
  int i = (blockIdx.x * 256 + threadIdx.x) * 4;
  if (i >= n) return;
  float4 v = *(const float4*)(src + i);
  u16x4 o;
  o[0] = (u16)f2bf(v.x); o[1] = (u16)f2bf(v.y);
  o[2] = (u16)f2bf(v.z); o[3] = (u16)f2bf(v.w);
  *(u16x4*)(dst + i) = o;
}

// ---- prep: W [K][N] f32  ->  Wt [N][K] bf16, LDS-tiled transpose ----
__global__ __launch_bounds__(256) void tr_k(
    const float* __restrict__ W0, const float* __restrict__ W1,
    const float* __restrict__ W2, const float* __restrict__ W3,
    const float* __restrict__ W4, const float* __restrict__ W5,
    u16* __restrict__ T0, u16* __restrict__ T1, u16* __restrict__ T2,
    u16* __restrict__ T3, u16* __restrict__ T4, u16* __restrict__ T5,
    int K, int N)
{
  int z = blockIdx.z;
  const float* W = (z==0)?W0:(z==1)?W1:(z==2)?W2:(z==3)?W3:(z==4)?W4:W5;
  u16*         T = (z==0)?T0:(z==1)?T1:(z==2)?T2:(z==3)?T3:(z==4)?T4:T5;

  __shared__ float tile[32][33];
  int n0 = blockIdx.x * 32, k0 = blockIdx.y * 32;
  int tx = threadIdx.x & 31, ty = threadIdx.x >> 5;  // 32 x 8
#pragma unroll
  for (int i = 0; i < 32; i += 8)
    tile[ty + i][tx] = W[(size_t)(k0 + ty + i) * N + n0 + tx];
  __syncthreads();
#pragma unroll
  for (int i = 0; i < 32; i += 8)
    T[(size_t)(n0 + ty + i) * K + k0 + tx] = (u16)f2bf(tile[tx][ty + i]);
}

// ---- GEMM: C = act(A_bf16[MxK] @ Wt_bf16[N][K]^T + bias) ----
// LDS-staged 64x64 tile, BK=64, reg-prefetch, XOR-swizzled LDS layout.
template<bool RELU, bool SPLIT3>
__global__ __launch_bounds__(256) void gemm_k(
    const u16* __restrict__ A, int K,
    const u16* __restrict__ T0, const u16* __restrict__ T1, const u16* __restrict__ T2,
    const float* __restrict__ B0, const float* __restrict__ B1, const float* __restrict__ B2,
    float* __restrict__ C0f, u16* __restrict__ C0b,
    u16* __restrict__ C1, u16* __restrict__ C2)
{
  __shared__ u16 As[64*64];
  __shared__ u16 Bs[64*64];

  int bm = blockIdx.x;
  int nglob = blockIdx.y * 64;
  int sel  = SPLIT3 ? (nglob >> 9) : 0;
  int ncol = nglob & 511;
  const u16*   T  = (sel==0) ? T0 : (sel==1) ? T1 : T2;
  const float* Bv = (sel==0) ? B0 : (sel==1) ? B1 : B2;

  int t = threadIdx.x;
  int wave = t >> 6, lane = t & 63;
  int wm = (wave >> 1) * 32, wn = (wave & 1) * 32;
  int lr = lane & 15, kg = lane >> 4;

  int o0 = t*16, o1 = 4096 + t*16;
  int r0 = o0 >> 7, cb0 = o0 & 127;
  int r1 = o1 >> 7, cb1 = o1 & 127;
  const char* Ag0 = (const char*)(A + (size_t)(bm*64 + r0) * K) + cb0;
  const char* Ag1 = (const char*)(A + (size_t)(bm*64 + r1) * K) + cb1;
  const char* Bg0 = (const char*)(T + (size_t)(ncol  + r0) * K) + cb0;
  const char* Bg1 = (const char*)(T + (size_t)(ncol  + r1) * K) + cb1;
  char* Ad0 = (char*)As + r0*128 + (cb0 ^ ((r0 & 7) << 4));
  char* Ad1 = (char*)As + r1*128 + (cb1 ^ ((r1 & 7) << 4));
  char* Bd0 = (char*)Bs + r0*128 + (cb0 ^ ((r0 & 7) << 4));
  char* Bd1 = (char*)Bs + r1*128 + (cb1 ^ ((r1 & 7) << 4));

  int sw = (lr & 7) << 4;
  const char* Afr0 = (const char*)As + (wm + lr) * 128;
  const char* Afr1 = (const char*)As + (wm + 16 + lr) * 128;
  const char* Bfr0 = (const char*)Bs + (wn + lr) * 128;
  const char* Bfr1 = (const char*)Bs + (wn + 16 + lr) * 128;

  f32x4 acc[2][2] = {};

  short8 pa0 = *(const short8*)Ag0;
  short8 pa1 = *(const short8*)Ag1;
  short8 pb0 = *(const short8*)Bg0;
  short8 pb1 = *(const short8*)Bg1;

  for (int k0 = 0; k0 < K; k0 += 64) {
    __syncthreads();
    *(short8*)Ad0 = pa0;  *(short8*)Ad1 = pa1;
    *(short8*)Bd0 = pb0;  *(short8*)Bd1 = pb1;
    __syncthreads();
    int kn = k0 + 64;
    if (kn < K) {
      pa0 = *(const short8*)(Ag0 + kn*2);
      pa1 = *(const short8*)(Ag1 + kn*2);
      pb0 = *(const short8*)(Bg0 + kn*2);
      pb1 = *(const short8*)(Bg1 + kn*2);
    }
#pragma unroll
    for (int ks = 0; ks < 2; ++ks) {
      int cb = (ks*64 + kg*16) ^ sw;
      short8 af0 = *(const short8*)(Afr0 + cb);
      short8 af1 = *(const short8*)(Afr1 + cb);
      short8 bf0 = *(const short8*)(Bfr0 + cb);
      short8 bf1 = *(const short8*)(Bfr1 + cb);
      acc[0][0] = __builtin_amdgcn_mfma_f32_16x16x32_bf16(af0, bf0, acc[0][0], 0, 0, 0);
      acc[0][1] = __builtin_amdgcn_mfma_f32_16x16x32_bf16(af0, bf1, acc[0][1], 0, 0, 0);
      acc[1][0] = __builtin_amdgcn_mfma_f32_16x16x32_bf16(af1, bf0, acc[1][0], 0, 0, 0);
      acc[1][1] = __builtin_amdgcn_mfma_f32_16x16x32_bf16(af1, bf1, acc[1][1], 0, 0, 0);
    }
  }

#pragma unroll
  for (int mi = 0; mi < 2; ++mi)
#pragma unroll
    for (int ni = 0; ni < 2; ++ni) {
      int col = ncol + wn + ni*16 + lr;
      float bia = Bv[col];
#pragma unroll
      for (int r = 0; r < 4; ++r) {
        int row = bm*64 + wm + mi*16 + kg*4 + r;
        float vv = acc[mi][ni][r] + bia;
        if (RELU) vv = fmaxf(vv, 0.f);
        if (SPLIT3) {
          u16* C = (sel==0) ? C0b : (sel==1) ? C1 : C2;
          C[(size_t)row*512 + col] = (u16)f2bf(vv);
        } else {
          C0f[(size_t)row*512 + col] = vv;
          C0b[(size_t)row*512 + col] = (u16)f2bf(vv);
        }
      }
    }
}

// ---- attention: 512 threads/block (8 waves), wave w = head w ----
// K staged reg->LDS (pitch 1040B, bank-rotated); q in regs; V prefetched
// to regs (never through LDS); softmax via shfl; fused residual+LN.
template<int KLOC>
__global__ __launch_bounds__(512, 4) void attn_k(
    const u16* __restrict__ Qb, const u16* __restrict__ Kb, const u16* __restrict__ Vb,
    const int* __restrict__ Aidx,
    const float* __restrict__ resid,
    const float* __restrict__ gma, const float* __restrict__ bta,
    float* __restrict__ outp, u16* __restrict__ outb, float* __restrict__ attOut)
{
  constexpr int PITCH_B = 1040;          // bytes per K row in LDS (rot 4 words)
  constexpr int NP  = KLOC / 16;         // energy passes (1 or 4)
  constexpr int NV  = KLOC / 8;          // V-prefetch regs (2 or 8)
  constexpr int RPW = KLOC / 8;          // K rows staged per wave (2 or 8)

  __shared__ u16   k_s[KLOC * (PITCH_B/2)];
  __shared__ float o_s[512];
  __shared__ int   idx_s[KLOC];
  __shared__ float red_s[16];

  int n = blockIdx.x;
  int t = threadIdx.x;
  int w = t >> 6;          // wave id = head
  int lane = t & 63;

  if (t < KLOC) idx_s[t] = Aidx[(size_t)n*64 + t];
  __syncthreads();

  // ---- stage K: wave w loads rows [w*RPW, w*RPW+RPW), lane covers 16B ----
  int rowbase = w * RPW;
  short8 kreg[RPW];
#pragma unroll
  for (int i = 0; i < RPW; ++i)
    kreg[i] = ((const short8*)(Kb + (size_t)idx_s[rowbase + i] * 512))[lane];
#pragma unroll
  for (int i = 0; i < RPW; ++i)
    *(short8*)((char*)k_s + (size_t)(rowbase + i) * PITCH_B + lane * 16) = kreg[i];

  // ---- prefetch V (per-lane gather, head w slice) while K settles ----
  int jg = lane >> 3, dc = lane & 7;
  short8 vpre[NV];
#pragma unroll
  for (int p = 0; p < NV; ++p) {
    int r = p * 8 + jg;
    vpre[p] = *(const short8*)(Vb + (size_t)idx_s[r] * 512 + w * 64 + dc * 8);
  }

  // ---- q into regs: lane=(jj=lane&15, dq=lane>>4) holds 16 dims ----
  int jj = lane & 15, dq = lane >> 4;
  float qreg[16];
  {
    const u16* qp = Qb + (size_t)n*512 + w*64 + dq*16;
    short8 qa = *(const short8*)qp;
    short8 qb2 = *(const short8*)(qp + 8);
#pragma unroll
    for (int i = 0; i < 8; ++i) {
      qreg[i]     = bf2f((u16)qa[i]);
      qreg[8 + i] = bf2f((u16)qb2[i]);
    }
  }
  __syncthreads();   // K staged

  // ---- energies: key jj (+16 per pass), dims [dq*16, dq*16+16) ----
  float att[NP];
#pragma unroll
  for (int p = 0; p < NP; ++p) {
    int row = p * 16 + jj;
    const u16* kp = (const u16*)((const char*)k_s + (size_t)row * PITCH_B)
                    + w * 64 + dq * 16;
    short8 k0 = *(const short8*)kp;
    short8 k1 = *(const short8*)(kp + 8);
    float e = 0.f;
#pragma unroll
    for (int i = 0; i < 8; ++i) {
      e = fmaf(qreg[i],     bf2f((u16)k0[i]), e);
      e = fmaf(qreg[8 + i], bf2f((u16)k1[i]), e);
    }
    e += __shfl_xor(e, 16);   // fold dq bit0
    e += __shfl_xor(e, 32);   // fold dq bit1
    att[p] = e;
  }

  // ---- softmax over KLOC keys (16-lane groups own distinct keys) ----
  float mx = att[0];
#pragma unroll
  for (int p = 1; p < NP; ++p) mx = fmaxf(mx, att[p]);
  mx = fmaxf(mx, __shfl_xor(mx, 1)); mx = fmaxf(mx, __shfl_xor(mx, 2));
  mx = fmaxf(mx, __shfl_xor(mx, 4)); mx = fmaxf(mx, __shfl_xor(mx, 8));
  float s = 0.f;
#pragma unroll
  for (int p = 0; p < NP; ++p) { att[p] = __expf(att[p] - mx); s += att[p]; }
  s += __shfl_xor(s, 1); s += __shfl_xor(s, 2);
  s += __shfl_xor(s, 4); s += __shfl_xor(s, 8);
  float inv = 1.f / (s * SCALE);
#pragma unroll
  for (int p = 0; p < NP; ++p) att[p] *= inv;

  // ---- PV: lane=(jg,dc); att via shfl (owner lane = key&15) ----
  float vacc[8] = {0.f,0.f,0.f,0.f,0.f,0.f,0.f,0.f};
#pragma unroll
  for (int p = 0; p < NV; ++p) {
    float a = __shfl(att[p >> 1], (p & 1) * 8 + jg);
#pragma unroll
    for (int i = 0; i < 8; ++i)
      vacc[i] = fmaf(a, bf2f((u16)vpre[p][i]), vacc[i]);
  }
#pragma unroll
  for (int i = 0; i < 8; ++i) {
    vacc[i] += __shfl_xor(vacc[i], 8);
    vacc[i] += __shfl_xor(vacc[i], 16);
    vacc[i] += __shfl_xor(vacc[i], 32);
  }
  if (jg == 0) {
#pragma unroll
    for (int i = 0; i < 8; ++i)
      o_s[w*64 + dc*8 + i] = vacc[i];
  }
  __syncthreads();

  // ---- residual + LayerNorm (1 element per thread) ----
  float x = o_s[t] + __builtin_nontemporal_load(resid + (size_t)n*512 + t);
  float su = x, sq = x * x;
  su += __shfl_xor(su, 1);  sq += __shfl_xor(sq, 1);
  su += __shfl_xor(su, 2);  sq += __shfl_xor(sq, 2);
  su += __shfl_xor(su, 4);  sq += __shfl_xor(sq, 4);
  su += __shfl_xor(su, 8);  sq += __shfl_xor(sq, 8);
  su += __shfl_xor(su, 16); sq += __shfl_xor(sq, 16);
  su += __shfl_xor(su, 32); sq += __shfl_xor(sq, 32);
  if (lane == 0) { red_s[w] = su; red_s[8 + w] = sq; }
  __syncthreads();
  float tot = 0.f, tots = 0.f;
#pragma unroll
  for (int i = 0; i < 8; ++i) { tot += red_s[i]; tots += red_s[8 + i]; }
  float mean = tot  * (1.0f/512.0f);
  float var  = tots * (1.0f/512.0f) - mean*mean;
  float rstd = rsqrtf(var + LNEPS);
  float y = (x - mean) * rstd * gma[t] + bta[t];
  __builtin_nontemporal_store(y, outp + (size_t)n*512 + t);
  if (outb != nullptr) outb[(size_t)n*512 + t] = (u16)f2bf(y);
  if (attOut != nullptr && t == 0) attOut[n] = 8.0f / SCALE;
}

extern "C" void kernel_launch(void* const* d_in, const int* in_sizes, int n_in,
                              void* d_out, int out_size, void* d_ws, size_t ws_size,
                              hipStream_t stream)
{
  const float* x   = (const float*)d_in[0];
  const int*   A   = (const int*)  d_in[1];
  const float* Wfc = (const float*)d_in[2];
  const float* bfc = (const float*)d_in[3];
  const float* Wq1 = (const float*)d_in[4];
  const float* bq1 = (const float*)d_in[5];
  const float* Wk1 = (const float*)d_in[6];
  const float* bk1 = (const float*)d_in[7];
  const float* Wv1 = (const float*)d_in[8];
  const float* bv1 = (const float*)d_in[9];
  const float* g1  = (const float*)d_in[10];
  const float* be1 = (const float*)d_in[11];
  const float* Wq2 = (const float*)d_in[12];
  const float* bq2 = (const float*)d_in[13];
  const float* Wk2 = (const float*)d_in[14];
  const float* bk2 = (const float*)d_in[15];
  const float* Wv2 = (const float*)d_in[16];
  const float* bv2 = (const float*)d_in[17];
  const float* g2  = (const float*)d_in[18];
  const float* be2 = (const float*)d_in[19];

  char* ws = (char*)d_ws;
  const size_t SZ = (size_t)2048*512;
  float* embs = (float*)ws;                    ws += SZ*4;
  float* b1   = (float*)ws;                    ws += SZ*4;
  u16* embs_b = (u16*)ws;                      ws += SZ*2;
  u16* b1_b   = (u16*)ws;                      ws += SZ*2;
  u16* qb     = (u16*)ws;                      ws += SZ*2;
  u16* kb     = (u16*)ws;                      ws += SZ*2;
  u16* vb     = (u16*)ws;                      ws += SZ*2;
  u16* xb     = (u16*)ws;                      ws += (size_t)2048*1024*2;
  u16* t_fc   = (u16*)ws;                      ws += (size_t)512*1024*2;
  u16* t_q1   = (u16*)ws;                      ws += (size_t)512*512*2;
  u16* t_k1   = (u16*)ws;                      ws += (size_t)512*512*2;
  u16* t_v1   = (u16*)ws;                      ws += (size_t)512*512*2;
  u16* t_q2   = (u16*)ws;                      ws += (size_t)512*512*2;
  u16* t_k2   = (u16*)ws;                      ws += (size_t)512*512*2;
  u16* t_v2   = (u16*)ws;                      ws += (size_t)512*512*2;

  float* out  = (float*)d_out;
  float* att2 = out + SZ;

  dim3 blk(256);
  cvt_k<<<dim3(2048), blk, 0, stream>>>(x, xb, 2048*1024);
  tr_k<<<dim3(16, 32, 1), blk, 0, stream>>>(Wfc, Wfc, Wfc, Wfc, Wfc, Wfc,
      t_fc, t_fc, t_fc, t_fc, t_fc, t_fc, 1024, 512);
  tr_k<<<dim3(16, 16, 6), blk, 0, stream>>>(Wq1, Wk1, Wv1, Wq2, Wk2, Wv2,
      t_q1, t_k1, t_v1, t_q2, t_k2, t_v2, 512, 512);

  gemm_k<true,false><<<dim3(32, 8), blk, 0, stream>>>(xb, 1024,
      t_fc, nullptr, nullptr, bfc, nullptr, nullptr, embs, embs_b, nullptr, nullptr);
  gemm_k<false,true><<<dim3(32, 24), blk, 0, stream>>>(embs_b, 512,
      t_q1, t_k1, t_v1, bq1, bk1, bv1, nullptr, qb, kb, vb);
  attn_k<16><<<dim3(2048), dim3(512), 0, stream>>>(qb, kb, vb, A, embs, g1, be1, b1, b1_b, nullptr);
  gemm_k<false,true><<<dim3(32, 24), blk, 0, stream>>>(b1_b, 512,
      t_q2, t_k2, t_v2, bq2, bk2, bv2, nullptr, qb, kb, vb);
  attn_k<64><<<dim3(2048), dim3(512), 0, stream>>>(qb, kb, vb, A, b1, g2, be2, out, nullptr, att2);
}

// Round 11
// 172.196 us; speedup vs baseline: 2.4063x; 1.0145x over previous
//
#include <hip/hip_runtime.h>

#define SCALE 22.627416997969522f
#define LNEPS 1e-5f
#define NTOK 2048

using short8 = __attribute__((ext_vector_type(8))) short;
using f32x4  = __attribute__((ext_vector_type(4))) float;
typedef unsigned short u16;
using u16x4 = __attribute__((ext_vector_type(4))) u16;

static __device__ __forceinline__ u16 f2bf(float f){
  unsigned u = __builtin_bit_cast(unsigned, f);
  u += 0x7FFFu + ((u >> 16) & 1u);
  return (u16)(u >> 16);
}
static __device__ __forceinline__ float bf2f(u16 u){
  unsigned v = ((unsigned)u) << 16;
  return __builtin_bit_cast(float, v);
}

// ---- prep: plain f32 -> bf16 convert (vectorized) ----
__global__ __launch_bounds__(256) void cvt_k(const float* __restrict__ src,
                                             u16* __restrict__ dst, int n)
{
  int i = (blockIdx.x * 256 + threadIdx.x) * 4;
  if (i >= n) return;
  float4 v = *(const float4*)(src + i);
  u16x4 o;
  o[0] = f2bf(v.x); o[1] = f2bf(v.y); o[2] = f2bf(v.z); o[3] = f2bf(v.w);
  *(u16x4*)(dst + i) = o;
}

// ---- prep: all 7 weights W [K][N] f32 -> Wt [N][K] bf16 in ONE launch ----
__global__ __launch_bounds__(256) void tr_k(
    const float* __restrict__ Wfc,
    const float* __restrict__ W1, const float* __restrict__ W2,
    const float* __restrict__ W3, const float* __restrict__ W4,
    const float* __restrict__ W5, const float* __restrict__ W6,
    u16* __restrict__ Tfc,
    u16* __restrict__ T1, u16* __restrict__ T2, u16* __restrict__ T3,
    u16* __restrict__ T4, u16* __restrict__ T5, u16* __restrict__ T6)
{
  int z = blockIdx.z;
  const float* W; u16* T; int K, N;
  if (z == 0) { W = Wfc; T = Tfc; K = 1024; N = 512; }
  else {
    K = 512; N = 512;
    switch (z) {
      case 1: W = W1; T = T1; break;
      case 2: W = W2; T = T2; break;
      case 3: W = W3; T = T3; break;
      case 4: W = W4; T = T4; break;
      case 5: W = W5; T = T5; break;
      default: W = W6; T = T6; break;
    }
    if ((int)blockIdx.y >= 16) return;   // 512x512 needs only 16 k-tiles
  }
  __shared__ float tile[32][33];
  int n0 = blockIdx.x * 32, k0 = blockIdx.y * 32;
  int tx = threadIdx.x & 31, ty = threadIdx.x >> 5;  // 32 x 8
#pragma unroll
  for (int i = 0; i < 32; i += 8)
    tile[ty + i][tx] = W[(size_t)(k0 + ty + i) * N + n0 + tx];
  __syncthreads();
#pragma unroll
  for (int i = 0; i < 32; i += 8)
    T[(size_t)(n0 + ty + i) * K + k0 + tx] = f2bf(tile[tx][ty + i]);
}

// ---- GEMM: C = act(A_bf16[MxK] @ Wt_bf16[N][K]^T + bias) ----
// LDS-staged 64x64 tile, BK=64, reg-prefetch, XOR-swizzled LDS layout.
// SPLIT3: sel0 -> token-major bf16 (q); sel1/2 -> HEAD-MAJOR [h][n][64] (k,v).
template<bool RELU, bool SPLIT3>
__global__ __launch_bounds__(256) void gemm_k(
    const u16* __restrict__ A, int K,
    const u16* __restrict__ T0, const u16* __restrict__ T1, const u16* __restrict__ T2,
    const float* __restrict__ B0, const float* __restrict__ B1, const float* __restrict__ B2,
    float* __restrict__ C0f, u16* __restrict__ C0b,
    u16* __restrict__ C1, u16* __restrict__ C2)
{
  __shared__ u16 As[64*64];
  __shared__ u16 Bs[64*64];

  int bm = blockIdx.x;
  int nglob = blockIdx.y * 64;
  int sel  = SPLIT3 ? (nglob >> 9) : 0;
  int ncol = nglob & 511;
  const u16*   T  = (sel==0) ? T0 : (sel==1) ? T1 : T2;
  const float* Bv = (sel==0) ? B0 : (sel==1) ? B1 : B2;

  int t = threadIdx.x;
  int wave = t >> 6, lane = t & 63;
  int wm = (wave >> 1) * 32, wn = (wave & 1) * 32;
  int lr = lane & 15, kg = lane >> 4;

  int o0 = t*16, o1 = 4096 + t*16;
  int r0 = o0 >> 7, cb0 = o0 & 127;
  int r1 = o1 >> 7, cb1 = o1 & 127;
  const char* Ag0 = (const char*)(A + (size_t)(bm*64 + r0) * K) + cb0;
  const char* Ag1 = (const char*)(A + (size_t)(bm*64 + r1) * K) + cb1;
  const char* Bg0 = (const char*)(T + (size_t)(ncol  + r0) * K) + cb0;
  const char* Bg1 = (const char*)(T + (size_t)(ncol  + r1) * K) + cb1;
  char* Ad0 = (char*)As + r0*128 + (cb0 ^ ((r0 & 7) << 4));
  char* Ad1 = (char*)As + r1*128 + (cb1 ^ ((r1 & 7) << 4));
  char* Bd0 = (char*)Bs + r0*128 + (cb0 ^ ((r0 & 7) << 4));
  char* Bd1 = (char*)Bs + r1*128 + (cb1 ^ ((r1 & 7) << 4));

  int sw = (lr & 7) << 4;
  const char* Afr0 = (const char*)As + (wm + lr) * 128;
  const char* Afr1 = (const char*)As + (wm + 16 + lr) * 128;
  const char* Bfr0 = (const char*)Bs + (wn + lr) * 128;
  const char* Bfr1 = (const char*)Bs + (wn + 16 + lr) * 128;

  f32x4 acc[2][2] = {};

  short8 pa0 = *(const short8*)Ag0;
  short8 pa1 = *(const short8*)Ag1;
  short8 pb0 = *(const short8*)Bg0;
  short8 pb1 = *(const short8*)Bg1;

  for (int k0 = 0; k0 < K; k0 += 64) {
    __syncthreads();
    *(short8*)Ad0 = pa0;  *(short8*)Ad1 = pa1;
    *(short8*)Bd0 = pb0;  *(short8*)Bd1 = pb1;
    __syncthreads();
    int kn = k0 + 64;
    if (kn < K) {
      pa0 = *(const short8*)(Ag0 + kn*2);
      pa1 = *(const short8*)(Ag1 + kn*2);
      pb0 = *(const short8*)(Bg0 + kn*2);
      pb1 = *(const short8*)(Bg1 + kn*2);
    }
#pragma unroll
    for (int ks = 0; ks < 2; ++ks) {
      int cb = (ks*64 + kg*16) ^ sw;
      short8 af0 = *(const short8*)(Afr0 + cb);
      short8 af1 = *(const short8*)(Afr1 + cb);
      short8 bf0 = *(const short8*)(Bfr0 + cb);
      short8 bf1 = *(const short8*)(Bfr1 + cb);
      acc[0][0] = __builtin_amdgcn_mfma_f32_16x16x32_bf16(af0, bf0, acc[0][0], 0, 0, 0);
      acc[0][1] = __builtin_amdgcn_mfma_f32_16x16x32_bf16(af0, bf1, acc[0][1], 0, 0, 0);
      acc[1][0] = __builtin_amdgcn_mfma_f32_16x16x32_bf16(af1, bf0, acc[1][0], 0, 0, 0);
      acc[1][1] = __builtin_amdgcn_mfma_f32_16x16x32_bf16(af1, bf1, acc[1][1], 0, 0, 0);
    }
  }

#pragma unroll
  for (int mi = 0; mi < 2; ++mi)
#pragma unroll
    for (int ni = 0; ni < 2; ++ni) {
      int col = ncol + wn + ni*16 + lr;
      float bia = Bv[col];
#pragma unroll
      for (int r = 0; r < 4; ++r) {
        int row = bm*64 + wm + mi*16 + kg*4 + r;
        float vv = acc[mi][ni][r] + bia;
        if (RELU) vv = fmaxf(vv, 0.f);
        if (SPLIT3) {
          if (sel == 0) {
            C0b[(size_t)row*512 + col] = f2bf(vv);           // q token-major
          } else {
            u16* C = (sel == 1) ? C1 : C2;                   // k/v head-major
            C[((size_t)(col >> 6) * NTOK + row) * 64 + (col & 63)] = f2bf(vv);
          }
        } else {
          C0f[(size_t)row*512 + col] = vv;
          C0b[(size_t)row*512 + col] = f2bf(vv);
        }
      }
    }
}

// ---- attention: 512 thr (8 waves), wave = head; K/V HEAD-MAJOR [h][n][64].
// No LDS staging: every gather instr touches full 128B lines only.
template<int KLOC>
__global__ __launch_bounds__(512, 4) void attn_k(
    const u16* __restrict__ Qb, const u16* __restrict__ Kh, const u16* __restrict__ Vh,
    const int* __restrict__ Aidx,
    const float* __restrict__ resid,
    const float* __restrict__ gma, const float* __restrict__ bta,
    float* __restrict__ outp, u16* __restrict__ outb, float* __restrict__ attOut)
{
  constexpr int NP = KLOC / 16;          // energy passes (1 or 4)
  constexpr int NV = KLOC / 8;           // V-prefetch regs (2 or 8)

  __shared__ float o_s[512];
  __shared__ int   idx_s[KLOC];
  __shared__ float red_s[16];

  int n = blockIdx.x;
  int t = threadIdx.x;
  int w = t >> 6;          // wave id = head
  int lane = t & 63;

  if (t < KLOC) idx_s[t] = Aidx[(size_t)n*64 + t];
  __syncthreads();

  const u16* Kbase = Kh + (size_t)w * NTOK * 64;
  const u16* Vbase = Vh + (size_t)w * NTOK * 64;
  int jj = lane & 15, dq = lane >> 4;    // energy mapping
  int jg = lane >> 3, dc = lane & 7;     // PV mapping

  // ---- V prefetch: 8 lanes cover one 128B row -> 8 full lines / instr ----
  short8 vpre[NV];
#pragma unroll
  for (int p = 0; p < NV; ++p)
    vpre[p] = *(const short8*)(Vbase + (size_t)idx_s[p*8 + jg] * 64 + dc*8);

  // ---- q into regs: lane (jj,dq) holds dims [dq*16, dq*16+16) ----
  float qreg[16];
  {
    const u16* qp = Qb + (size_t)n*512 + w*64 + dq*16;
    short8 qa = *(const short8*)qp;
    short8 qb2 = *(const short8*)(qp + 8);
#pragma unroll
    for (int i = 0; i < 8; ++i) {
      qreg[i]     = bf2f((u16)qa[i]);
      qreg[8 + i] = bf2f((u16)qb2[i]);
    }
  }

  // ---- energies: 4 lanes (dq) cover one K row -> 16 full lines / instr ----
  float att[NP];
#pragma unroll
  for (int p = 0; p < NP; ++p) {
    const u16* kp = Kbase + (size_t)idx_s[p*16 + jj] * 64 + dq*16;
    short8 k0 = *(const short8*)kp;
    short8 k1 = *(const short8*)(kp + 8);
    float e = 0.f;
#pragma unroll
    for (int i = 0; i < 8; ++i) {
      e = fmaf(qreg[i],     bf2f((u16)k0[i]), e);
      e = fmaf(qreg[8 + i], bf2f((u16)k1[i]), e);
    }
    e += __shfl_xor(e, 16);   // fold dq bit0
    e += __shfl_xor(e, 32);   // fold dq bit1
    att[p] = e;
  }

  // ---- softmax over KLOC keys (16-lane groups own distinct keys) ----
  float mx = att[0];
#pragma unroll
  for (int p = 1; p < NP; ++p) mx = fmaxf(mx, att[p]);
  mx = fmaxf(mx, __shfl_xor(mx, 1)); mx = fmaxf(mx, __shfl_xor(mx, 2));
  mx = fmaxf(mx, __shfl_xor(mx, 4)); mx = fmaxf(mx, __shfl_xor(mx, 8));
  float s = 0.f;
#pragma unroll
  for (int p = 0; p < NP; ++p) { att[p] = __expf(att[p] - mx); s += att[p]; }
  s += __shfl_xor(s, 1); s += __shfl_xor(s, 2);
  s += __shfl_xor(s, 4); s += __shfl_xor(s, 8);
  float inv = 1.f / (s * SCALE);
#pragma unroll
  for (int p = 0; p < NP; ++p) att[p] *= inv;

  // ---- PV: att via shfl (owner lane = key & 15) ----
  float vacc[8] = {0.f,0.f,0.f,0.f,0.f,0.f,0.f,0.f};
#pragma unroll
  for (int p = 0; p < NV; ++p) {
    float a = __shfl(att[p >> 1], (p & 1) * 8 + jg);
#pragma unroll
    for (int i = 0; i < 8; ++i)
      vacc[i] = fmaf(a, bf2f((u16)vpre[p][i]), vacc[i]);
  }
#pragma unroll
  for (int i = 0; i < 8; ++i) {
    vacc[i] += __shfl_xor(vacc[i], 8);
    vacc[i] += __shfl_xor(vacc[i], 16);
    vacc[i] += __shfl_xor(vacc[i], 32);
  }
  if (jg == 0) {
#pragma unroll
    for (int i = 0; i < 8; ++i)
      o_s[w*64 + dc*8 + i] = vacc[i];
  }
  __syncthreads();

  // ---- residual + LayerNorm (1 element per thread) ----
  float x = o_s[t] + __builtin_nontemporal_load(resid + (size_t)n*512 + t);
  float su = x, sq = x * x;
  su += __shfl_xor(su, 1);  sq += __shfl_xor(sq, 1);
  su += __shfl_xor(su, 2);  sq += __shfl_xor(sq, 2);
  su += __shfl_xor(su, 4);  sq += __shfl_xor(sq, 4);
  su += __shfl_xor(su, 8);  sq += __shfl_xor(sq, 8);
  su += __shfl_xor(su, 16); sq += __shfl_xor(sq, 16);
  su += __shfl_xor(su, 32); sq += __shfl_xor(sq, 32);
  if (lane == 0) { red_s[w] = su; red_s[8 + w] = sq; }
  __syncthreads();
  float tot = 0.f, tots = 0.f;
#pragma unroll
  for (int i = 0; i < 8; ++i) { tot += red_s[i]; tots += red_s[8 + i]; }
  float mean = tot  * (1.0f/512.0f);
  float var  = tots * (1.0f/512.0f) - mean*mean;
  float rstd = rsqrtf(var + LNEPS);
  float y = (x - mean) * rstd * gma[t] + bta[t];
  __builtin_nontemporal_store(y, outp + (size_t)n*512 + t);
  if (outb != nullptr) outb[(size_t)n*512 + t] = f2bf(y);
  if (attOut != nullptr && t == 0) attOut[n] = 8.0f / SCALE;
}

extern "C" void kernel_launch(void* const* d_in, const int* in_sizes, int n_in,
                              void* d_out, int out_size, void* d_ws, size_t ws_size,
                              hipStream_t stream)
{
  const float* x   = (const float*)d_in[0];
  const int*   A   = (const int*)  d_in[1];
  const float* Wfc = (const float*)d_in[2];
  const float* bfc = (const float*)d_in[3];
  const float* Wq1 = (const float*)d_in[4];
  const float* bq1 = (const float*)d_in[5];
  const float* Wk1 = (const float*)d_in[6];
  const float* bk1 = (const float*)d_in[7];
  const float* Wv1 = (const float*)d_in[8];
  const float* bv1 = (const float*)d_in[9];
  const float* g1  = (const float*)d_in[10];
  const float* be1 = (const float*)d_in[11];
  const float* Wq2 = (const float*)d_in[12];
  const float* bq2 = (const float*)d_in[13];
  const float* Wk2 = (const float*)d_in[14];
  const float* bk2 = (const float*)d_in[15];
  const float* Wv2 = (const float*)d_in[16];
  const float* bv2 = (const float*)d_in[17];
  const float* g2  = (const float*)d_in[18];
  const float* be2 = (const float*)d_in[19];

  char* ws = (char*)d_ws;
  const size_t SZ = (size_t)NTOK*512;
  float* embs = (float*)ws;                    ws += SZ*4;
  float* b1   = (float*)ws;                    ws += SZ*4;
  u16* embs_b = (u16*)ws;                      ws += SZ*2;
  u16* b1_b   = (u16*)ws;                      ws += SZ*2;
  u16* qb     = (u16*)ws;                      ws += SZ*2;
  u16* kb     = (u16*)ws;                      ws += SZ*2;   // head-major [8][2048][64]
  u16* vb     = (u16*)ws;                      ws += SZ*2;   // head-major
  u16* xb     = (u16*)ws;                      ws += (size_t)NTOK*1024*2;
  u16* t_fc   = (u16*)ws;                      ws += (size_t)512*1024*2;
  u16* t_q1   = (u16*)ws;                      ws += (size_t)512*512*2;
  u16* t_k1   = (u16*)ws;                      ws += (size_t)512*512*2;
  u16* t_v1   = (u16*)ws;                      ws += (size_t)512*512*2;
  u16* t_q2   = (u16*)ws;                      ws += (size_t)512*512*2;
  u16* t_k2   = (u16*)ws;                      ws += (size_t)512*512*2;
  u16* t_v2   = (u16*)ws;                      ws += (size_t)512*512*2;

  float* out  = (float*)d_out;
  float* att2 = out + SZ;

  dim3 blk(256);
  cvt_k<<<dim3(2048), blk, 0, stream>>>(x, xb, NTOK*1024);
  tr_k<<<dim3(16, 32, 7), blk, 0, stream>>>(Wfc, Wq1, Wk1, Wv1, Wq2, Wk2, Wv2,
      t_fc, t_q1, t_k1, t_v1, t_q2, t_k2, t_v2);

  gemm_k<true,false><<<dim3(32, 8), blk, 0, stream>>>(xb, 1024,
      t_fc, nullptr, nullptr, bfc, nullptr, nullptr, embs, embs_b, nullptr, nullptr);
  gemm_k<false,true><<<dim3(32, 24), blk, 0, stream>>>(embs_b, 512,
      t_q1, t_k1, t_v1, bq1, bk1, bv1, nullptr, qb, kb, vb);
  attn_k<16><<<dim3(2048), dim3(512), 0, stream>>>(qb, kb, vb, A, embs, g1, be1, b1, b1_b, nullptr);
  gemm_k<false,true><<<dim3(32, 24), blk, 0, stream>>>(b1_b, 512,
      t_q2, t_k2, t_v2, bq2, bk2, bv2, nullptr, qb, kb, vb);
  attn_k<64><<<dim3(2048), dim3(512), 0, stream>>>(qb, kb, vb, A, b1, g2, be2, out, nullptr, att2);
}